// Round 4
// baseline (1045.879 us; speedup 1.0000x reference)
//
#include <hip/hip_runtime.h>
#include <math.h>

#define DEVI __device__ __forceinline__
typedef float fv4 __attribute__((ext_vector_type(4)));

DEVI float sigm(float x){ return 1.f/(1.f+__expf(-x)); }

// ---- block-wide (256 thr) reduction of two sums --------------------------
DEVI void blockReduce2(float& s1, float& s2, float* red){
    #pragma unroll
    for (int m=1;m<64;m<<=1){ s1+=__shfl_xor(s1,m); s2+=__shfl_xor(s2,m); }
    const int w = threadIdx.x>>6;
    if ((threadIdx.x&63)==0){ red[w]=s1; red[8+w]=s2; }
    __syncthreads();
    s1 = red[0]+red[1]+red[2]+red[3];
    s2 = red[8]+red[9]+red[10]+red[11];
}

// ---- generic row LayerNorm ----------------------------------------------
__global__ __launch_bounds__(256) void ln_rows(const float* __restrict__ in,
                                               const float* __restrict__ g,
                                               const float* __restrict__ bt,
                                               float* __restrict__ out, int C){
    __shared__ float red[16];
    const size_t row = blockIdx.x;
    const float* x = in + row*(size_t)C;
    float s1=0.f, s2=0.f;
    for (int c=threadIdx.x; c<C; c+=256){ float v=x[c]; s1+=v; s2+=v*v; }
    blockReduce2(s1,s2,red);
    const float inv = 1.f/(float)C;
    const float mu = s1*inv;
    const float rs = rsqrtf(s2*inv - mu*mu + 1e-5f);
    float* o = out + row*(size_t)C;
    for (int c=threadIdx.x; c<C; c+=256){
        float y = (x[c]-mu)*rs;
        if (g)  y *= g[c];
        if (bt) y += bt[c];
        o[c] = y;
    }
}

// ---- K transpose: kT[b][d][j] = qkvg[b*1024+j][256+d] --------------------
__global__ __launch_bounds__(256) void ktrans(const float* __restrict__ qkvg,
                                              float* __restrict__ kT){
    __shared__ float tile[64][65];
    const int t = threadIdx.x;
    const int jt = blockIdx.x*64, dt = blockIdx.y*64, b = blockIdx.z;
    const int c = t & 63, r0 = t >> 6;
    #pragma unroll 4
    for (int rr=r0; rr<64; rr+=4)
        tile[rr][c] = qkvg[(size_t)((b<<10)+jt+rr)*1024 + 256 + dt + c];
    __syncthreads();
    #pragma unroll 4
    for (int rr=r0; rr<64; rr+=4)
        kT[((size_t)(b*256 + dt + rr))*1024 + jt + c] = tile[c][rr];
}

// ---- tiled f32 GEMM: C(MxN) = A(MxK) @ B(KxN), 64x64 tile, BK=16 --------
// MODE 0: C = A@B (+bias)          MODE 1: C = resid + (A@B)*mask[m]
// MODE 2: C = resid + sigmoid(gather*mask)*(A@B)*mask[m]
template<int MODE>
__global__ __launch_bounds__(256) void gemm_t(
    const float* __restrict__ A, int lda,
    const float* __restrict__ B, int ldb,
    float* __restrict__ C, int ldc,
    int M, int N, int K,
    const float* __restrict__ bias,
    const float* __restrict__ resid,
    const float* __restrict__ mask,
    const float* __restrict__ gsrc,
    const int* __restrict__ idxp)
{
    __shared__ float As[16][68];
    __shared__ float Bs[16][68];
    const int t = threadIdx.x;
    const int tx = t & 15, ty = t >> 4;
    const int bm = blockIdx.x * 64, bn = blockIdx.y * 64;
    const int am = t >> 2, akq = (t & 3) * 4;
    const int bk = t >> 4, bnq = (t & 15) * 4;
    float acc[4][4] = {};
    for (int kt = 0; kt < K; kt += 16) {
        const float4 va = *(const float4*)&A[(size_t)(bm+am)*lda + kt + akq];
        const float4 vb = *(const float4*)&B[(size_t)(kt+bk)*ldb + bn + bnq];
        As[akq+0][am]=va.x; As[akq+1][am]=va.y; As[akq+2][am]=va.z; As[akq+3][am]=va.w;
        *(float4*)&Bs[bk][bnq] = vb;
        __syncthreads();
        #pragma unroll
        for (int kk=0; kk<16; ++kk){
            const float4 af = *(const float4*)&As[kk][ty*4];
            const float4 bf = *(const float4*)&Bs[kk][tx*4];
            acc[0][0]+=af.x*bf.x; acc[0][1]+=af.x*bf.y; acc[0][2]+=af.x*bf.z; acc[0][3]+=af.x*bf.w;
            acc[1][0]+=af.y*bf.x; acc[1][1]+=af.y*bf.y; acc[1][2]+=af.y*bf.z; acc[1][3]+=af.y*bf.w;
            acc[2][0]+=af.z*bf.x; acc[2][1]+=af.z*bf.y; acc[2][2]+=af.z*bf.z; acc[2][3]+=af.z*bf.w;
            acc[3][0]+=af.w*bf.x; acc[3][1]+=af.w*bf.y; acc[3][2]+=af.w*bf.z; acc[3][3]+=af.w*bf.w;
        }
        __syncthreads();
    }
    #pragma unroll
    for (int i=0;i<4;++i){
        const int m = bm + ty*4 + i;
        #pragma unroll
        for (int jj=0;jj<4;++jj){
            const int n = bn + tx*4 + jj;
            float v = acc[i][jj];
            if (MODE==0){
                if (bias) v += bias[n];
                C[(size_t)m*ldc+n] = v;
            } else if (MODE==1){
                const float mi = mask[m];
                C[(size_t)m*ldc+n] = resid[(size_t)m*256+n] + v*mi;
            } else {
                const float mi = mask[m];
                const int id = idxp[m];
                const int bbi = m >> 10;
                const float cg = gsrc[((size_t)(bbi*256+id))*256 + n]*mi;
                C[(size_t)m*ldc+n] = resid[(size_t)m*256+n] + sigm(cg)*v*mi;
            }
        }
    }
}

// ---- dual-B GEMM: bmid = silu(A@B1) * (A@B2) ----------------------------
__global__ __launch_bounds__(256) void gemm_dual(
    const float* __restrict__ A, int lda,
    const float* __restrict__ B1, const float* __restrict__ B2, int ldb,
    float* __restrict__ C, int ldc,
    int M, int N, int K)
{
    __shared__ float As[16][68];
    __shared__ float B1s[16][68];
    __shared__ float B2s[16][68];
    const int t = threadIdx.x;
    const int tx = t & 15, ty = t >> 4;
    const int bm = blockIdx.x * 64, bn = blockIdx.y * 64;
    const int am = t >> 2, akq = (t & 3) * 4;
    const int bk = t >> 4, bnq = (t & 15) * 4;
    float acc1[4][4] = {};
    float acc2[4][4] = {};
    for (int kt = 0; kt < K; kt += 16) {
        const float4 va  = *(const float4*)&A [(size_t)(bm+am)*lda + kt + akq];
        const float4 vb1 = *(const float4*)&B1[(size_t)(kt+bk)*ldb + bn + bnq];
        const float4 vb2 = *(const float4*)&B2[(size_t)(kt+bk)*ldb + bn + bnq];
        As[akq+0][am]=va.x; As[akq+1][am]=va.y; As[akq+2][am]=va.z; As[akq+3][am]=va.w;
        *(float4*)&B1s[bk][bnq] = vb1;
        *(float4*)&B2s[bk][bnq] = vb2;
        __syncthreads();
        #pragma unroll
        for (int kk=0; kk<16; ++kk){
            const float4 af = *(const float4*)&As[kk][ty*4];
            const float4 b1 = *(const float4*)&B1s[kk][tx*4];
            const float4 b2 = *(const float4*)&B2s[kk][tx*4];
            acc1[0][0]+=af.x*b1.x; acc1[0][1]+=af.x*b1.y; acc1[0][2]+=af.x*b1.z; acc1[0][3]+=af.x*b1.w;
            acc1[1][0]+=af.y*b1.x; acc1[1][1]+=af.y*b1.y; acc1[1][2]+=af.y*b1.z; acc1[1][3]+=af.y*b1.w;
            acc1[2][0]+=af.z*b1.x; acc1[2][1]+=af.z*b1.y; acc1[2][2]+=af.z*b1.z; acc1[2][3]+=af.z*b1.w;
            acc1[3][0]+=af.w*b1.x; acc1[3][1]+=af.w*b1.y; acc1[3][2]+=af.w*b1.z; acc1[3][3]+=af.w*b1.w;
            acc2[0][0]+=af.x*b2.x; acc2[0][1]+=af.x*b2.y; acc2[0][2]+=af.x*b2.z; acc2[0][3]+=af.x*b2.w;
            acc2[1][0]+=af.y*b2.x; acc2[1][1]+=af.y*b2.y; acc2[1][2]+=af.y*b2.z; acc2[1][3]+=af.y*b2.w;
            acc2[2][0]+=af.z*b2.x; acc2[2][1]+=af.z*b2.y; acc2[2][2]+=af.z*b2.z; acc2[2][3]+=af.z*b2.w;
            acc2[3][0]+=af.w*b2.x; acc2[3][1]+=af.w*b2.y; acc2[3][2]+=af.w*b2.z; acc2[3][3]+=af.w*b2.w;
        }
        __syncthreads();
    }
    #pragma unroll
    for (int i=0;i<4;++i){
        const int m = bm + ty*4 + i;
        #pragma unroll
        for (int jj=0;jj<4;++jj){
            const int n = bn + tx*4 + jj;
            const float u1 = acc1[i][jj];
            C[(size_t)m*ldc+n] = u1*sigm(u1)*acc2[i][jj];
        }
    }
}

// ---- fused attention: 1 query row per block ------------------------------
// qkvg row layout: [q 0..255 | k 256..511 | v 512..767 | gate_pre 768..1023]
// kT layout: [b][d=256][j=1024] (K transposed for coalesced QK^T reads)
// fp is streamed NON-TEMPORALLY (read-once, 512 MB) so kT/V stay L2/L3-hot.
__global__ __launch_bounds__(256,4) void attn_row(
    const float* __restrict__ qkvg,
    const float* __restrict__ kT,
    const float* __restrict__ fp,
    const float* __restrict__ lnzg, const float* __restrict__ lnzb,
    const float* __restrict__ wbias,
    const float* __restrict__ mask,
    float* __restrict__ og)
{
    __shared__ float S[8][1032];
    __shared__ float Qs[256];
    __shared__ float wbs[64*12];
    __shared__ float2 lglb[64];
    __shared__ float denomS[8];
    const int t = threadIdx.x;
    const int i = blockIdx.x;        // global row (b*1024 + n)
    const int b = i >> 10;
    Qs[t] = qkvg[(size_t)i*1024 + t];
    for (int idx=t; idx<512; idx+=256) wbs[(idx>>3)*12 + (idx&7)] = wbias[idx];
    if (t < 64) lglb[t] = make_float2(lnzg[t], lnzb[t]);
    __syncthreads();
    const int h = t >> 5, jl = t & 31;
    const float mi = mask[i];

    // ---- Phase A1: QK^T via transposed K (coalesced float2 loads) -------
    float q[32];
    #pragma unroll
    for (int d4=0; d4<8; ++d4){
        const float4 a = *(const float4*)&Qs[h*32 + d4*4];
        q[d4*4+0]=a.x; q[d4*4+1]=a.y; q[d4*4+2]=a.z; q[d4*4+3]=a.w;
    }
    const float scale = 0.17677669529663687f; // 1/sqrt(32)
    const float* kTb = kT + ((size_t)b*256 + h*32)*1024;
    for (int jt=0; jt<1024; jt+=64){
        const int j0 = jt + jl*2;
        float a0=0.f, a1=0.f;
        #pragma unroll
        for (int d=0; d<32; ++d){
            const float2 k2 = *(const float2*)(kTb + (size_t)d*1024 + j0);
            a0 += q[d]*k2.x; a1 += q[d]*k2.y;
        }
        *(float2*)&S[h][j0] = make_float2(a0*scale, a1*scale);
    }
    __syncthreads();

    // ---- Phase A2: pair-bias LN + Wbias + mask (4-lane groups) ----------
    // group g handles column j; lane l4 owns channels {c4*16 + l4*4 + 0..3}.
    // Per-instruction (fixed c4) the group's loads cover contiguous 64B ->
    // each cache sector is touched by exactly one nt instruction; the two
    // halves of a 128B line issue back-to-back (MSHR-merged). Prefetch next
    // j-tile into registers so HBM latency hides under the LN+matvec work.
    {
        const int g = t >> 2, l4 = t & 3;
        const size_t fpbase = (size_t)i * 65536;  // 1024*64
        fv4 nxt0, nxt1, nxt2, nxt3;
        {
            const fv4* r0 = (const fv4*)(fp + fpbase + (size_t)g*64);
            nxt0 = __builtin_nontemporal_load(r0 + 0*4 + l4);
            nxt1 = __builtin_nontemporal_load(r0 + 1*4 + l4);
            nxt2 = __builtin_nontemporal_load(r0 + 2*4 + l4);
            nxt3 = __builtin_nontemporal_load(r0 + 3*4 + l4);
        }
        #pragma unroll 1
        for (int jt=0; jt<1024; jt+=64){
            const int j = jt + g;
            const fv4 f0=nxt0, f1=nxt1, f2=nxt2, f3=nxt3;
            if (jt+64 < 1024){
                const fv4* rn = (const fv4*)(fp + fpbase + (size_t)(jt+64+g)*64);
                nxt0 = __builtin_nontemporal_load(rn + 0*4 + l4);
                nxt1 = __builtin_nontemporal_load(rn + 1*4 + l4);
                nxt2 = __builtin_nontemporal_load(rn + 2*4 + l4);
                nxt3 = __builtin_nontemporal_load(rn + 3*4 + l4);
            }
            float vv[16];
            vv[0]=f0.x; vv[1]=f0.y; vv[2]=f0.z; vv[3]=f0.w;
            vv[4]=f1.x; vv[5]=f1.y; vv[6]=f1.z; vv[7]=f1.w;
            vv[8]=f2.x; vv[9]=f2.y; vv[10]=f2.z; vv[11]=f2.w;
            vv[12]=f3.x; vv[13]=f3.y; vv[14]=f3.z; vv[15]=f3.w;
            float s1 = 0.f;
            #pragma unroll
            for (int c=0;c<16;++c) s1 += vv[c];
            s1 += __shfl_xor(s1,1); s1 += __shfl_xor(s1,2);
            const float mu = s1*(1.f/64.f);
            float s2=0.f;
            #pragma unroll
            for (int c=0;c<16;++c){ const float d=vv[c]-mu; vv[c]=d; s2+=d*d; }
            s2 += __shfl_xor(s2,1); s2 += __shfl_xor(s2,2);
            const float rs = rsqrtf(s2*(1.f/64.f)+1e-5f);
            float pb[8] = {};
            #pragma unroll
            for (int c4=0;c4<4;++c4){
                #pragma unroll
                for (int cc=0;cc<4;++cc){
                    const int c = c4*16 + l4*4 + cc;
                    const float2 gb2 = lglb[c];
                    const float lnv = vv[c4*4+cc]*rs*gb2.x + gb2.y;
                    const float4 w0 = *(const float4*)&wbs[c*12];
                    const float4 w1 = *(const float4*)&wbs[c*12+4];
                    pb[0]+=lnv*w0.x; pb[1]+=lnv*w0.y; pb[2]+=lnv*w0.z; pb[3]+=lnv*w0.w;
                    pb[4]+=lnv*w1.x; pb[5]+=lnv*w1.y; pb[6]+=lnv*w1.z; pb[7]+=lnv*w1.w;
                }
            }
            #pragma unroll
            for (int hh=0;hh<8;++hh){
                pb[hh] += __shfl_xor(pb[hh],1);
                pb[hh] += __shfl_xor(pb[hh],2);
            }
            const float mterm = (mi*mask[(b<<10)+j]-1.f)*100000.f;
            S[2*l4+0][j] += pb[2*l4+0] + mterm;
            S[2*l4+1][j] += pb[2*l4+1] + mterm;
        }
    }
    __syncthreads();

    // ---- Phase B: per-head softmax (32 lanes per head) ------------------
    {
        float mx = -3.4e38f;
        for (int jj=jl; jj<1024; jj+=32) mx = fmaxf(mx, S[h][jj]);
        #pragma unroll
        for (int off=16; off>0; off>>=1) mx = fmaxf(mx, __shfl_xor(mx, off, 32));
        float sum = 0.f;
        for (int jj=jl; jj<1024; jj+=32){
            const float e = __expf(S[h][jj]-mx);
            S[h][jj] = e;
            sum += e;
        }
        #pragma unroll
        for (int off=16; off>0; off>>=1) sum += __shfl_xor(sum, off, 32);
        if (jl==0) denomS[h] = sum;
    }
    __syncthreads();

    // ---- Phase C: PV (V reads coalesced across block) + gate ------------
    float o=0.f;
    const float* vcol = qkvg + ((size_t)(b<<10))*1024 + 512 + t;
    #pragma unroll 2
    for (int j=0; j<1024; j+=4){
        const float4 p = *(const float4*)&S[h][j];
        const float v0 = vcol[(size_t)(j+0)*1024];
        const float v1 = vcol[(size_t)(j+1)*1024];
        const float v2 = vcol[(size_t)(j+2)*1024];
        const float v3 = vcol[(size_t)(j+3)*1024];
        o += p.x*v0 + p.y*v1 + p.z*v2 + p.w*v3;
    }
    const float gpre = qkvg[(size_t)i*1024 + 768 + t];
    og[(size_t)i*256 + t] = (o/denomS[h]) * sigm(gpre);
}

// ---- sa = LN(rig)*sigmoid(cond_gate) + cond_bias -------------------------
__global__ __launch_bounds__(256) void sa_kernel(
    const float* __restrict__ rig,
    const float* __restrict__ c1res,
    const float* __restrict__ cbres,
    const int* __restrict__ idxp,
    const float* __restrict__ mask,
    float* __restrict__ sa)
{
    __shared__ float red[16];
    const int m = blockIdx.x;
    const int t = threadIdx.x;
    const float v = rig[(size_t)m*256 + t];
    float s1 = v, s2 = v*v;
    blockReduce2(s1,s2,red);
    const float mu = s1*(1.f/256.f);
    const float rs = rsqrtf(s2*(1.f/256.f) - mu*mu + 1e-5f);
    const float sn = (v-mu)*rs;
    const float mi = mask[m];
    const int id = idxp[m];
    const int b = m >> 10;
    const size_t go = ((size_t)(b*256+id))*256 + t;
    const float cgate = c1res[go]*mi;
    const float cb    = cbres[go]*mi;
    sa[(size_t)m*256+t] = sn*sigm(cgate) + cb;
}

extern "C" void kernel_launch(void* const* d_in, const int* in_sizes, int n_in,
                              void* d_out, int out_size, void* d_ws, size_t ws_size,
                              hipStream_t stream)
{
    (void)in_sizes; (void)n_in; (void)out_size; (void)ws_size;
    const float* s_     = (const float*)d_in[0];
    const float* rigids = (const float*)d_in[1];
    const float* fp     = (const float*)d_in[2];
    const float* maskp  = (const float*)d_in[3];
    const int*   idxp   = (const int*)d_in[4];
    const float* ln_g   = (const float*)d_in[5];
    const float* ln_b   = (const float*)d_in[6];
    const float* Wq     = (const float*)d_in[7];
    const float* Wkv    = (const float*)d_in[8];
    const float* lnz_g  = (const float*)d_in[9];
    const float* lnz_b  = (const float*)d_in[10];
    const float* Wbias  = (const float*)d_in[11];
    const float* Wg     = (const float*)d_in[12];
    const float* Wo     = (const float*)d_in[13];
    const float* lncond = (const float*)d_in[14];
    const float* Wc1    = (const float*)d_in[15];
    const float* bc1    = (const float*)d_in[16];
    const float* Wcn    = (const float*)d_in[17];
    const float* W1     = (const float*)d_in[18];
    const float* W2     = (const float*)d_in[19];
    const float* Wc2    = (const float*)d_in[20];
    const float* bc2    = (const float*)d_in[21];
    const float* Wb     = (const float*)d_in[22];
    float* out = (float*)d_out;

    float* ws    = (float*)d_ws;
    float* x     = ws;                  // 2048*256
    float* qkvg  = x     + 524288;      // 2048*1024
    float* ogb   = qkvg  + 2097152;     // 2048*256
    float* rig   = ogb   + 524288;      // 2048*256
    float* cn    = rig   + 524288;      // 512*384
    float* c1res = cn    + 196608;      // 512*256
    float* cbres = c1res + 131072;      // 512*256
    float* cgres = cbres + 131072;      // 512*256
    float* sab   = cgres + 131072;      // 2048*256
    float* bmid  = sab   + 524288;      // 2048*512
    float* kT    = bmid  + 1048576;     // 2*256*1024
    // total ~25.4 MB of d_ws

    ln_rows<<<2048,256,0,stream>>>(rigids, ln_g, ln_b, x, 256);
    gemm_t<0><<<dim3(32,4),256,0,stream>>>(x,256, Wq,256,  qkvg,     1024, 2048,256,256, nullptr,nullptr,nullptr,nullptr,nullptr);
    gemm_t<0><<<dim3(32,8),256,0,stream>>>(x,256, Wkv,512, qkvg+256, 1024, 2048,512,256, nullptr,nullptr,nullptr,nullptr,nullptr);
    gemm_t<0><<<dim3(32,4),256,0,stream>>>(x,256, Wg,256,  qkvg+768, 1024, 2048,256,256, nullptr,nullptr,nullptr,nullptr,nullptr);
    ktrans<<<dim3(16,4,2),256,0,stream>>>(qkvg, kT);
    attn_row<<<2048,256,0,stream>>>(qkvg, kT, fp, lnz_g, lnz_b, Wbias, maskp, ogb);
    gemm_t<1><<<dim3(32,4),256,0,stream>>>(ogb,256, Wo,256, rig,256, 2048,256,256, nullptr, rigids, maskp, nullptr,nullptr);
    ln_rows<<<512,256,0,stream>>>(s_, lncond, nullptr, cn, 384);
    gemm_t<0><<<dim3(8,4),256,0,stream>>>(cn,384, Wc1,256, c1res,256, 512,256,384, bc1,    nullptr,nullptr,nullptr,nullptr);
    gemm_t<0><<<dim3(8,4),256,0,stream>>>(cn,384, Wcn,256, cbres,256, 512,256,384, nullptr,nullptr,nullptr,nullptr,nullptr);
    gemm_t<0><<<dim3(8,4),256,0,stream>>>(s_,384, Wc2,256, cgres,256, 512,256,384, bc2,    nullptr,nullptr,nullptr,nullptr);
    sa_kernel<<<2048,256,0,stream>>>(rig, c1res, cbres, idxp, maskp, sab);
    gemm_dual<<<dim3(32,8),256,0,stream>>>(sab,256, W1, W2, 512, bmid,512, 2048,512,256);
    gemm_t<2><<<dim3(32,4),256,0,stream>>>(bmid,512, Wb,256, out,256, 2048,256,512, nullptr, rig, maskp, cgres, idxp);
}

// Round 5
// 924.735 us; speedup vs baseline: 1.1310x; 1.1310x over previous
//
#include <hip/hip_runtime.h>
#include <math.h>

#define DEVI __device__ __forceinline__
typedef float fv4 __attribute__((ext_vector_type(4)));

DEVI float sigm(float x){ return 1.f/(1.f+__expf(-x)); }

// ---- block-wide (256 thr) reduction of two sums --------------------------
DEVI void blockReduce2(float& s1, float& s2, float* red){
    #pragma unroll
    for (int m=1;m<64;m<<=1){ s1+=__shfl_xor(s1,m); s2+=__shfl_xor(s2,m); }
    const int w = threadIdx.x>>6;
    if ((threadIdx.x&63)==0){ red[w]=s1; red[8+w]=s2; }
    __syncthreads();
    s1 = red[0]+red[1]+red[2]+red[3];
    s2 = red[8]+red[9]+red[10]+red[11];
}

// ---- generic row LayerNorm ----------------------------------------------
__global__ __launch_bounds__(256) void ln_rows(const float* __restrict__ in,
                                               const float* __restrict__ g,
                                               const float* __restrict__ bt,
                                               float* __restrict__ out, int C){
    __shared__ float red[16];
    const size_t row = blockIdx.x;
    const float* x = in + row*(size_t)C;
    float s1=0.f, s2=0.f;
    for (int c=threadIdx.x; c<C; c+=256){ float v=x[c]; s1+=v; s2+=v*v; }
    blockReduce2(s1,s2,red);
    const float inv = 1.f/(float)C;
    const float mu = s1*inv;
    const float rs = rsqrtf(s2*inv - mu*mu + 1e-5f);
    float* o = out + row*(size_t)C;
    for (int c=threadIdx.x; c<C; c+=256){
        float y = (x[c]-mu)*rs;
        if (g)  y *= g[c];
        if (bt) y += bt[c];
        o[c] = y;
    }
}

// ---- K transpose: kT[b][d][j] = qkvg[b*1024+j][256+d] --------------------
__global__ __launch_bounds__(256) void ktrans(const float* __restrict__ qkvg,
                                              float* __restrict__ kT){
    __shared__ float tile[64][65];
    const int t = threadIdx.x;
    const int jt = blockIdx.x*64, dt = blockIdx.y*64, b = blockIdx.z;
    const int c = t & 63, r0 = t >> 6;
    #pragma unroll 4
    for (int rr=r0; rr<64; rr+=4)
        tile[rr][c] = qkvg[(size_t)((b<<10)+jt+rr)*1024 + 256 + dt + c];
    __syncthreads();
    #pragma unroll 4
    for (int rr=r0; rr<64; rr+=4)
        kT[((size_t)(b*256 + dt + rr))*1024 + jt + c] = tile[c][rr];
}

// ---- tiled f32 GEMM: C(MxN) = A(MxK) @ B(KxN), 64x64 tile, BK=16 --------
// MODE 0: C = A@B (+bias)          MODE 1: C = resid + (A@B)*mask[m]
// MODE 2: C = resid + sigmoid(gather*mask)*(A@B)*mask[m]
template<int MODE>
__global__ __launch_bounds__(256) void gemm_t(
    const float* __restrict__ A, int lda,
    const float* __restrict__ B, int ldb,
    float* __restrict__ C, int ldc,
    int M, int N, int K,
    const float* __restrict__ bias,
    const float* __restrict__ resid,
    const float* __restrict__ mask,
    const float* __restrict__ gsrc,
    const int* __restrict__ idxp)
{
    __shared__ float As[16][68];
    __shared__ float Bs[16][68];
    const int t = threadIdx.x;
    const int tx = t & 15, ty = t >> 4;
    const int bm = blockIdx.x * 64, bn = blockIdx.y * 64;
    const int am = t >> 2, akq = (t & 3) * 4;
    const int bk = t >> 4, bnq = (t & 15) * 4;
    float acc[4][4] = {};
    for (int kt = 0; kt < K; kt += 16) {
        const float4 va = *(const float4*)&A[(size_t)(bm+am)*lda + kt + akq];
        const float4 vb = *(const float4*)&B[(size_t)(kt+bk)*ldb + bn + bnq];
        As[akq+0][am]=va.x; As[akq+1][am]=va.y; As[akq+2][am]=va.z; As[akq+3][am]=va.w;
        *(float4*)&Bs[bk][bnq] = vb;
        __syncthreads();
        #pragma unroll
        for (int kk=0; kk<16; ++kk){
            const float4 af = *(const float4*)&As[kk][ty*4];
            const float4 bf = *(const float4*)&Bs[kk][tx*4];
            acc[0][0]+=af.x*bf.x; acc[0][1]+=af.x*bf.y; acc[0][2]+=af.x*bf.z; acc[0][3]+=af.x*bf.w;
            acc[1][0]+=af.y*bf.x; acc[1][1]+=af.y*bf.y; acc[1][2]+=af.y*bf.z; acc[1][3]+=af.y*bf.w;
            acc[2][0]+=af.z*bf.x; acc[2][1]+=af.z*bf.y; acc[2][2]+=af.z*bf.z; acc[2][3]+=af.z*bf.w;
            acc[3][0]+=af.w*bf.x; acc[3][1]+=af.w*bf.y; acc[3][2]+=af.w*bf.z; acc[3][3]+=af.w*bf.w;
        }
        __syncthreads();
    }
    #pragma unroll
    for (int i=0;i<4;++i){
        const int m = bm + ty*4 + i;
        #pragma unroll
        for (int jj=0;jj<4;++jj){
            const int n = bn + tx*4 + jj;
            float v = acc[i][jj];
            if (MODE==0){
                if (bias) v += bias[n];
                C[(size_t)m*ldc+n] = v;
            } else if (MODE==1){
                const float mi = mask[m];
                C[(size_t)m*ldc+n] = resid[(size_t)m*256+n] + v*mi;
            } else {
                const float mi = mask[m];
                const int id = idxp[m];
                const int bbi = m >> 10;
                const float cg = gsrc[((size_t)(bbi*256+id))*256 + n]*mi;
                C[(size_t)m*ldc+n] = resid[(size_t)m*256+n] + sigm(cg)*v*mi;
            }
        }
    }
}

// ---- dual-B GEMM: bmid = silu(A@B1) * (A@B2) ----------------------------
__global__ __launch_bounds__(256) void gemm_dual(
    const float* __restrict__ A, int lda,
    const float* __restrict__ B1, const float* __restrict__ B2, int ldb,
    float* __restrict__ C, int ldc,
    int M, int N, int K)
{
    __shared__ float As[16][68];
    __shared__ float B1s[16][68];
    __shared__ float B2s[16][68];
    const int t = threadIdx.x;
    const int tx = t & 15, ty = t >> 4;
    const int bm = blockIdx.x * 64, bn = blockIdx.y * 64;
    const int am = t >> 2, akq = (t & 3) * 4;
    const int bk = t >> 4, bnq = (t & 15) * 4;
    float acc1[4][4] = {};
    float acc2[4][4] = {};
    for (int kt = 0; kt < K; kt += 16) {
        const float4 va  = *(const float4*)&A [(size_t)(bm+am)*lda + kt + akq];
        const float4 vb1 = *(const float4*)&B1[(size_t)(kt+bk)*ldb + bn + bnq];
        const float4 vb2 = *(const float4*)&B2[(size_t)(kt+bk)*ldb + bn + bnq];
        As[akq+0][am]=va.x; As[akq+1][am]=va.y; As[akq+2][am]=va.z; As[akq+3][am]=va.w;
        *(float4*)&B1s[bk][bnq] = vb1;
        *(float4*)&B2s[bk][bnq] = vb2;
        __syncthreads();
        #pragma unroll
        for (int kk=0; kk<16; ++kk){
            const float4 af = *(const float4*)&As[kk][ty*4];
            const float4 b1 = *(const float4*)&B1s[kk][tx*4];
            const float4 b2 = *(const float4*)&B2s[kk][tx*4];
            acc1[0][0]+=af.x*b1.x; acc1[0][1]+=af.x*b1.y; acc1[0][2]+=af.x*b1.z; acc1[0][3]+=af.x*b1.w;
            acc1[1][0]+=af.y*b1.x; acc1[1][1]+=af.y*b1.y; acc1[1][2]+=af.y*b1.z; acc1[1][3]+=af.y*b1.w;
            acc1[2][0]+=af.z*b1.x; acc1[2][1]+=af.z*b1.y; acc1[2][2]+=af.z*b1.z; acc1[2][3]+=af.z*b1.w;
            acc1[3][0]+=af.w*b1.x; acc1[3][1]+=af.w*b1.y; acc1[3][2]+=af.w*b1.z; acc1[3][3]+=af.w*b1.w;
            acc2[0][0]+=af.x*b2.x; acc2[0][1]+=af.x*b2.y; acc2[0][2]+=af.x*b2.z; acc2[0][3]+=af.x*b2.w;
            acc2[1][0]+=af.y*b2.x; acc2[1][1]+=af.y*b2.y; acc2[1][2]+=af.y*b2.z; acc2[1][3]+=af.y*b2.w;
            acc2[2][0]+=af.z*b2.x; acc2[2][1]+=af.z*b2.y; acc2[2][2]+=af.z*b2.z; acc2[2][3]+=af.z*b2.w;
            acc2[3][0]+=af.w*b2.x; acc2[3][1]+=af.w*b2.y; acc2[3][2]+=af.w*b2.z; acc2[3][3]+=af.w*b2.w;
        }
        __syncthreads();
    }
    #pragma unroll
    for (int i=0;i<4;++i){
        const int m = bm + ty*4 + i;
        #pragma unroll
        for (int jj=0;jj<4;++jj){
            const int n = bn + tx*4 + jj;
            const float u1 = acc1[i][jj];
            C[(size_t)m*ldc+n] = u1*sigm(u1)*acc2[i][jj];
        }
    }
}

// ---- pair-bias precompute: pb[b][h][i][j] = LN(fp)@Wbias + maskterm ------
// Pure streaming kernel: reads fp once (512 MB, coalesced 1KB/wave-instr),
// writes pb once (64 MB, coalesced). block = (b,i); 64 groups x 4 lanes.
__global__ __launch_bounds__(256,4) void pb_kernel(
    const float* __restrict__ fp,
    const float* __restrict__ lnzg, const float* __restrict__ lnzb,
    const float* __restrict__ wbias,
    const float* __restrict__ mask,
    float* __restrict__ pb)
{
    __shared__ float S[8][1032];
    __shared__ float wbs[64*12];
    __shared__ float2 lglb[64];
    const int t = threadIdx.x;
    const int bi = blockIdx.x;       // b*1024 + i
    const int b = bi >> 10, i = bi & 1023;
    for (int idx=t; idx<512; idx+=256) wbs[(idx>>3)*12 + (idx&7)] = wbias[idx];
    if (t < 64) lglb[t] = make_float2(lnzg[t], lnzb[t]);
    __syncthreads();
    const float mi = mask[bi];
    const int g = t >> 2, l4 = t & 3;
    const size_t fpbase = (size_t)bi * 65536;  // 1024*64
    #pragma unroll 1
    for (int jt=0; jt<1024; jt+=64){
        const int j = jt + g;
        const fv4* fprow4 = (const fv4*)(fp + fpbase + (size_t)j*64);
        float vv[16];
        float s1 = 0.f;
        #pragma unroll
        for (int c4=0;c4<4;++c4){
            const fv4 f4 = fprow4[c4*4 + l4];
            vv[c4*4+0]=f4.x; vv[c4*4+1]=f4.y; vv[c4*4+2]=f4.z; vv[c4*4+3]=f4.w;
            s1 += f4.x+f4.y+f4.z+f4.w;
        }
        s1 += __shfl_xor(s1,1); s1 += __shfl_xor(s1,2);
        const float mu = s1*(1.f/64.f);
        float s2=0.f;
        #pragma unroll
        for (int c=0;c<16;++c){ const float d=vv[c]-mu; vv[c]=d; s2+=d*d; }
        s2 += __shfl_xor(s2,1); s2 += __shfl_xor(s2,2);
        const float rs = rsqrtf(s2*(1.f/64.f)+1e-5f);
        float pbv[8] = {};
        #pragma unroll
        for (int c4=0;c4<4;++c4){
            #pragma unroll
            for (int cc=0;cc<4;++cc){
                const int c = c4*16 + l4*4 + cc;
                const float2 gb2 = lglb[c];
                const float lnv = vv[c4*4+cc]*rs*gb2.x + gb2.y;
                const float4 w0 = *(const float4*)&wbs[c*12];
                const float4 w1 = *(const float4*)&wbs[c*12+4];
                pbv[0]+=lnv*w0.x; pbv[1]+=lnv*w0.y; pbv[2]+=lnv*w0.z; pbv[3]+=lnv*w0.w;
                pbv[4]+=lnv*w1.x; pbv[5]+=lnv*w1.y; pbv[6]+=lnv*w1.z; pbv[7]+=lnv*w1.w;
            }
        }
        #pragma unroll
        for (int hh=0;hh<8;++hh){
            pbv[hh] += __shfl_xor(pbv[hh],1);
            pbv[hh] += __shfl_xor(pbv[hh],2);
        }
        const float mterm = (mi*mask[(b<<10)+j]-1.f)*100000.f;
        S[2*l4+0][j] = pbv[2*l4+0] + mterm;
        S[2*l4+1][j] = pbv[2*l4+1] + mterm;
    }
    __syncthreads();
    // coalesced write-out: thread t covers consecutive j within each h-plane
    #pragma unroll 1
    for (int idx=t; idx<8192; idx+=256){
        const int h = idx >> 10, j = idx & 1023;
        pb[(((size_t)(b*8+h))*1024 + i)*1024 + j] = S[h][j];
    }
}

// ---- attention: 8 query rows x 1 head per block; no barriers needed ------
// Each 32-lane group owns one query row end-to-end (QK^T, softmax, PV).
__global__ __launch_bounds__(256,4) void attn_tile(
    const float* __restrict__ qkvg,
    const float* __restrict__ kT,
    const float* __restrict__ pb,
    float* __restrict__ og)
{
    __shared__ float S[8][1032];
    __shared__ float qs[8][33];
    __shared__ float denomS[8];
    const int t = threadIdx.x;
    const int it = blockIdx.x;       // i-tile (8 rows) within batch
    const int h  = blockIdx.y;
    const int b  = blockIdx.z;
    const int i0 = it*8;
    const int r = t >> 5, jl = t & 31;
    // load Q fragment for this head (group r loads its own row)
    qs[r][jl] = qkvg[((size_t)(b*1024 + i0 + r))*1024 + h*32 + jl];
    float q[32];
    #pragma unroll
    for (int d=0; d<32; ++d) q[d] = qs[r][d];

    const float scale = 0.17677669529663687f; // 1/sqrt(32)
    const float* kTb = kT + ((size_t)b*256 + h*32)*1024;
    const float* pbr = pb + (((size_t)(b*8+h))*1024 + i0 + r)*1024;
    // QK^T + pair bias
    for (int jt=0; jt<1024; jt+=64){
        const int j0 = jt + jl*2;
        float a0=0.f, a1=0.f;
        #pragma unroll
        for (int d=0; d<32; ++d){
            const float2 k2 = *(const float2*)(kTb + (size_t)d*1024 + j0);
            a0 += q[d]*k2.x; a1 += q[d]*k2.y;
        }
        const float2 pb2 = *(const float2*)(pbr + j0);
        S[r][j0]   = a0*scale + pb2.x;
        S[r][j0+1] = a1*scale + pb2.y;
    }
    // softmax over the row (32-lane group)
    {
        float mx = -3.4e38f;
        for (int jj=jl; jj<1024; jj+=32) mx = fmaxf(mx, S[r][jj]);
        #pragma unroll
        for (int off=16; off>0; off>>=1) mx = fmaxf(mx, __shfl_xor(mx, off, 32));
        float sum = 0.f;
        for (int jj=jl; jj<1024; jj+=32){
            const float e = __expf(S[r][jj]-mx);
            S[r][jj] = e;
            sum += e;
        }
        #pragma unroll
        for (int off=16; off>0; off>>=1) sum += __shfl_xor(sum, off, 32);
        if (jl==0) denomS[r] = sum;
    }
    // PV: thread (r, d=jl) accumulates o[i0+r][h*32+d]
    float o = 0.f;
    const float* vcol = qkvg + ((size_t)(b*1024))*1024 + 512 + h*32 + jl;
    #pragma unroll 2
    for (int j=0; j<1024; j+=4){
        const float4 p = *(const float4*)&S[r][j];
        const float v0 = vcol[(size_t)(j+0)*1024];
        const float v1 = vcol[(size_t)(j+1)*1024];
        const float v2 = vcol[(size_t)(j+2)*1024];
        const float v3 = vcol[(size_t)(j+3)*1024];
        o += p.x*v0 + p.y*v1 + p.z*v2 + p.w*v3;
    }
    const int row = b*1024 + i0 + r;
    const float gpre = qkvg[(size_t)row*1024 + 768 + h*32 + jl];
    og[(size_t)row*256 + h*32 + jl] = (o/denomS[r]) * sigm(gpre);
}

// ---- sa = LN(rig)*sigmoid(cond_gate) + cond_bias -------------------------
__global__ __launch_bounds__(256) void sa_kernel(
    const float* __restrict__ rig,
    const float* __restrict__ c1res,
    const float* __restrict__ cbres,
    const int* __restrict__ idxp,
    const float* __restrict__ mask,
    float* __restrict__ sa)
{
    __shared__ float red[16];
    const int m = blockIdx.x;
    const int t = threadIdx.x;
    const float v = rig[(size_t)m*256 + t];
    float s1 = v, s2 = v*v;
    blockReduce2(s1,s2,red);
    const float mu = s1*(1.f/256.f);
    const float rs = rsqrtf(s2*(1.f/256.f) - mu*mu + 1e-5f);
    const float sn = (v-mu)*rs;
    const float mi = mask[m];
    const int id = idxp[m];
    const int b = m >> 10;
    const size_t go = ((size_t)(b*256+id))*256 + t;
    const float cgate = c1res[go]*mi;
    const float cb    = cbres[go]*mi;
    sa[(size_t)m*256+t] = sn*sigm(cgate) + cb;
}

extern "C" void kernel_launch(void* const* d_in, const int* in_sizes, int n_in,
                              void* d_out, int out_size, void* d_ws, size_t ws_size,
                              hipStream_t stream)
{
    (void)in_sizes; (void)n_in; (void)out_size; (void)ws_size;
    const float* s_     = (const float*)d_in[0];
    const float* rigids = (const float*)d_in[1];
    const float* fp     = (const float*)d_in[2];
    const float* maskp  = (const float*)d_in[3];
    const int*   idxp   = (const int*)d_in[4];
    const float* ln_g   = (const float*)d_in[5];
    const float* ln_b   = (const float*)d_in[6];
    const float* Wq     = (const float*)d_in[7];
    const float* Wkv    = (const float*)d_in[8];
    const float* lnz_g  = (const float*)d_in[9];
    const float* lnz_b  = (const float*)d_in[10];
    const float* Wbias  = (const float*)d_in[11];
    const float* Wg     = (const float*)d_in[12];
    const float* Wo     = (const float*)d_in[13];
    const float* lncond = (const float*)d_in[14];
    const float* Wc1    = (const float*)d_in[15];
    const float* bc1    = (const float*)d_in[16];
    const float* Wcn    = (const float*)d_in[17];
    const float* W1     = (const float*)d_in[18];
    const float* W2     = (const float*)d_in[19];
    const float* Wc2    = (const float*)d_in[20];
    const float* bc2    = (const float*)d_in[21];
    const float* Wb     = (const float*)d_in[22];
    float* out = (float*)d_out;

    float* ws    = (float*)d_ws;
    float* x     = ws;                  // 2048*256
    float* qkvg  = x     + 524288;      // 2048*1024
    float* ogb   = qkvg  + 2097152;     // 2048*256
    float* rig   = ogb   + 524288;      // 2048*256
    float* cn    = rig   + 524288;      // 512*384
    float* c1res = cn    + 196608;      // 512*256
    float* cbres = c1res + 131072;      // 512*256
    float* cgres = cbres + 131072;      // 512*256
    float* sab   = cgres + 131072;      // 2048*256
    float* bmid  = sab   + 524288;      // 2048*512
    float* kT    = bmid  + 1048576;     // 2*256*1024
    float* pbuf  = kT    + 524288;      // 2*8*1024*1024 = 64 MB
    // total ~92.5 MB of d_ws

    // pb stream FIRST so the 512 MB fp read cannot evict qkvg/kT later.
    pb_kernel<<<2048,256,0,stream>>>(fp, lnz_g, lnz_b, Wbias, maskp, pbuf);
    ln_rows<<<2048,256,0,stream>>>(rigids, ln_g, ln_b, x, 256);
    gemm_t<0><<<dim3(32,4),256,0,stream>>>(x,256, Wq,256,  qkvg,     1024, 2048,256,256, nullptr,nullptr,nullptr,nullptr,nullptr);
    gemm_t<0><<<dim3(32,8),256,0,stream>>>(x,256, Wkv,512, qkvg+256, 1024, 2048,512,256, nullptr,nullptr,nullptr,nullptr,nullptr);
    gemm_t<0><<<dim3(32,4),256,0,stream>>>(x,256, Wg,256,  qkvg+768, 1024, 2048,256,256, nullptr,nullptr,nullptr,nullptr,nullptr);
    ktrans<<<dim3(16,4,2),256,0,stream>>>(qkvg, kT);
    attn_tile<<<dim3(128,8,2),256,0,stream>>>(qkvg, kT, pbuf, ogb);
    gemm_t<1><<<dim3(32,4),256,0,stream>>>(ogb,256, Wo,256, rig,256, 2048,256,256, nullptr, rigids, maskp, nullptr,nullptr);
    ln_rows<<<512,256,0,stream>>>(s_, lncond, nullptr, cn, 384);
    gemm_t<0><<<dim3(8,4),256,0,stream>>>(cn,384, Wc1,256, c1res,256, 512,256,384, bc1,    nullptr,nullptr,nullptr,nullptr);
    gemm_t<0><<<dim3(8,4),256,0,stream>>>(cn,384, Wcn,256, cbres,256, 512,256,384, nullptr,nullptr,nullptr,nullptr,nullptr);
    gemm_t<0><<<dim3(8,4),256,0,stream>>>(s_,384, Wc2,256, cgres,256, 512,256,384, bc2,    nullptr,nullptr,nullptr,nullptr);
    sa_kernel<<<2048,256,0,stream>>>(rig, c1res, cbres, idxp, maskp, sab);
    gemm_dual<<<dim3(32,8),256,0,stream>>>(sab,256, W1, W2, 512, bmid,512, 2048,512,256);
    gemm_t<2><<<dim3(32,4),256,0,stream>>>(bmid,512, Wb,256, out,256, 2048,256,512, nullptr, rig, maskp, cgres, idxp);
}

// Round 6
// 606.515 us; speedup vs baseline: 1.7244x; 1.5247x over previous
//
#include <hip/hip_runtime.h>
#include <math.h>

#define DEVI __device__ __forceinline__
typedef float fv4 __attribute__((ext_vector_type(4)));

DEVI float sigm(float x){ return 1.f/(1.f+__expf(-x)); }

// ---- block-wide (256 thr) reduction of two sums --------------------------
DEVI void blockReduce2(float& s1, float& s2, float* red){
    #pragma unroll
    for (int m=1;m<64;m<<=1){ s1+=__shfl_xor(s1,m); s2+=__shfl_xor(s2,m); }
    const int w = threadIdx.x>>6;
    if ((threadIdx.x&63)==0){ red[w]=s1; red[8+w]=s2; }
    __syncthreads();
    s1 = red[0]+red[1]+red[2]+red[3];
    s2 = red[8]+red[9]+red[10]+red[11];
}

// ---- generic row LayerNorm ----------------------------------------------
__global__ __launch_bounds__(256) void ln_rows(const float* __restrict__ in,
                                               const float* __restrict__ g,
                                               const float* __restrict__ bt,
                                               float* __restrict__ out, int C){
    __shared__ float red[16];
    const size_t row = blockIdx.x;
    const float* x = in + row*(size_t)C;
    float s1=0.f, s2=0.f;
    for (int c=threadIdx.x; c<C; c+=256){ float v=x[c]; s1+=v; s2+=v*v; }
    blockReduce2(s1,s2,red);
    const float inv = 1.f/(float)C;
    const float mu = s1*inv;
    const float rs = rsqrtf(s2*inv - mu*mu + 1e-5f);
    float* o = out + row*(size_t)C;
    for (int c=threadIdx.x; c<C; c+=256){
        float y = (x[c]-mu)*rs;
        if (g)  y *= g[c];
        if (bt) y += bt[c];
        o[c] = y;
    }
}

// ---- K transpose: kT[b][d][j] = qkvg[b*1024+j][256+d] --------------------
__global__ __launch_bounds__(256) void ktrans(const float* __restrict__ qkvg,
                                              float* __restrict__ kT){
    __shared__ float tile[64][65];
    const int t = threadIdx.x;
    const int jt = blockIdx.x*64, dt = blockIdx.y*64, b = blockIdx.z;
    const int c = t & 63, r0 = t >> 6;
    #pragma unroll 4
    for (int rr=r0; rr<64; rr+=4)
        tile[rr][c] = qkvg[(size_t)((b<<10)+jt+rr)*1024 + 256 + dt + c];
    __syncthreads();
    #pragma unroll 4
    for (int rr=r0; rr<64; rr+=4)
        kT[((size_t)(b*256 + dt + rr))*1024 + jt + c] = tile[c][rr];
}

// ---- tiled f32 GEMM: C(MxN) = A(MxK) @ B(KxN), 64x64 tile, BK=16 --------
// MODE 0: C = A@B (+bias)          MODE 1: C = resid + (A@B)*mask[m]
// MODE 2: C = resid + sigmoid(gather*mask)*(A@B)*mask[m]
template<int MODE>
__global__ __launch_bounds__(256) void gemm_t(
    const float* __restrict__ A, int lda,
    const float* __restrict__ B, int ldb,
    float* __restrict__ C, int ldc,
    int M, int N, int K,
    const float* __restrict__ bias,
    const float* __restrict__ resid,
    const float* __restrict__ mask,
    const float* __restrict__ gsrc,
    const int* __restrict__ idxp)
{
    __shared__ float As[16][68];
    __shared__ float Bs[16][68];
    const int t = threadIdx.x;
    const int tx = t & 15, ty = t >> 4;
    const int bm = blockIdx.x * 64, bn = blockIdx.y * 64;
    const int am = t >> 2, akq = (t & 3) * 4;
    const int bk = t >> 4, bnq = (t & 15) * 4;
    float acc[4][4] = {};
    for (int kt = 0; kt < K; kt += 16) {
        const float4 va = *(const float4*)&A[(size_t)(bm+am)*lda + kt + akq];
        const float4 vb = *(const float4*)&B[(size_t)(kt+bk)*ldb + bn + bnq];
        As[akq+0][am]=va.x; As[akq+1][am]=va.y; As[akq+2][am]=va.z; As[akq+3][am]=va.w;
        *(float4*)&Bs[bk][bnq] = vb;
        __syncthreads();
        #pragma unroll
        for (int kk=0; kk<16; ++kk){
            const float4 af = *(const float4*)&As[kk][ty*4];
            const float4 bf = *(const float4*)&Bs[kk][tx*4];
            acc[0][0]+=af.x*bf.x; acc[0][1]+=af.x*bf.y; acc[0][2]+=af.x*bf.z; acc[0][3]+=af.x*bf.w;
            acc[1][0]+=af.y*bf.x; acc[1][1]+=af.y*bf.y; acc[1][2]+=af.y*bf.z; acc[1][3]+=af.y*bf.w;
            acc[2][0]+=af.z*bf.x; acc[2][1]+=af.z*bf.y; acc[2][2]+=af.z*bf.z; acc[2][3]+=af.z*bf.w;
            acc[3][0]+=af.w*bf.x; acc[3][1]+=af.w*bf.y; acc[3][2]+=af.w*bf.z; acc[3][3]+=af.w*bf.w;
        }
        __syncthreads();
    }
    #pragma unroll
    for (int i=0;i<4;++i){
        const int m = bm + ty*4 + i;
        #pragma unroll
        for (int jj=0;jj<4;++jj){
            const int n = bn + tx*4 + jj;
            float v = acc[i][jj];
            if (MODE==0){
                if (bias) v += bias[n];
                C[(size_t)m*ldc+n] = v;
            } else if (MODE==1){
                const float mi = mask[m];
                C[(size_t)m*ldc+n] = resid[(size_t)m*256+n] + v*mi;
            } else {
                const float mi = mask[m];
                const int id = idxp[m];
                const int bbi = m >> 10;
                const float cg = gsrc[((size_t)(bbi*256+id))*256 + n]*mi;
                C[(size_t)m*ldc+n] = resid[(size_t)m*256+n] + sigm(cg)*v*mi;
            }
        }
    }
}

// ---- dual-B GEMM: bmid = silu(A@B1) * (A@B2) ----------------------------
__global__ __launch_bounds__(256) void gemm_dual(
    const float* __restrict__ A, int lda,
    const float* __restrict__ B1, const float* __restrict__ B2, int ldb,
    float* __restrict__ C, int ldc,
    int M, int N, int K)
{
    __shared__ float As[16][68];
    __shared__ float B1s[16][68];
    __shared__ float B2s[16][68];
    const int t = threadIdx.x;
    const int tx = t & 15, ty = t >> 4;
    const int bm = blockIdx.x * 64, bn = blockIdx.y * 64;
    const int am = t >> 2, akq = (t & 3) * 4;
    const int bk = t >> 4, bnq = (t & 15) * 4;
    float acc1[4][4] = {};
    float acc2[4][4] = {};
    for (int kt = 0; kt < K; kt += 16) {
        const float4 va  = *(const float4*)&A [(size_t)(bm+am)*lda + kt + akq];
        const float4 vb1 = *(const float4*)&B1[(size_t)(kt+bk)*ldb + bn + bnq];
        const float4 vb2 = *(const float4*)&B2[(size_t)(kt+bk)*ldb + bn + bnq];
        As[akq+0][am]=va.x; As[akq+1][am]=va.y; As[akq+2][am]=va.z; As[akq+3][am]=va.w;
        *(float4*)&B1s[bk][bnq] = vb1;
        *(float4*)&B2s[bk][bnq] = vb2;
        __syncthreads();
        #pragma unroll
        for (int kk=0; kk<16; ++kk){
            const float4 af = *(const float4*)&As[kk][ty*4];
            const float4 b1 = *(const float4*)&B1s[kk][tx*4];
            const float4 b2 = *(const float4*)&B2s[kk][tx*4];
            acc1[0][0]+=af.x*b1.x; acc1[0][1]+=af.x*b1.y; acc1[0][2]+=af.x*b1.z; acc1[0][3]+=af.x*b1.w;
            acc1[1][0]+=af.y*b1.x; acc1[1][1]+=af.y*b1.y; acc1[1][2]+=af.y*b1.z; acc1[1][3]+=af.y*b1.w;
            acc1[2][0]+=af.z*b1.x; acc1[2][1]+=af.z*b1.y; acc1[2][2]+=af.z*b1.z; acc1[2][3]+=af.z*b1.w;
            acc1[3][0]+=af.w*b1.x; acc1[3][1]+=af.w*b1.y; acc1[3][2]+=af.w*b1.z; acc1[3][3]+=af.w*b1.w;
            acc2[0][0]+=af.x*b2.x; acc2[0][1]+=af.x*b2.y; acc2[0][2]+=af.x*b2.z; acc2[0][3]+=af.x*b2.w;
            acc2[1][0]+=af.y*b2.x; acc2[1][1]+=af.y*b2.y; acc2[1][2]+=af.y*b2.z; acc2[1][3]+=af.y*b2.w;
            acc2[2][0]+=af.z*b2.x; acc2[2][1]+=af.z*b2.y; acc2[2][2]+=af.z*b2.z; acc2[2][3]+=af.z*b2.w;
            acc2[3][0]+=af.w*b2.x; acc2[3][1]+=af.w*b2.y; acc2[3][2]+=af.w*b2.z; acc2[3][3]+=af.w*b2.w;
        }
        __syncthreads();
    }
    #pragma unroll
    for (int i=0;i<4;++i){
        const int m = bm + ty*4 + i;
        #pragma unroll
        for (int jj=0;jj<4;++jj){
            const int n = bn + tx*4 + jj;
            const float u1 = acc1[i][jj];
            C[(size_t)m*ldc+n] = u1*sigm(u1)*acc2[i][jj];
        }
    }
}

// ---- pair-bias precompute: pb[b][h][i][j] = LN(fp)@Wbias + maskterm ------
// 16-lane groups; every wave load/store instruction covers 1KB CONTIGUOUS.
// Per-lane channels c=4l..4l+3; weights held in VGPRs; head-reduce via
// 16-lane shfl reduce-scatter (lane l ends holding head h=(l>>1)&7).
__global__ __launch_bounds__(256,4) void pb_kernel(
    const float* __restrict__ fp,
    const float* __restrict__ lnzg, const float* __restrict__ lnzb,
    const float* __restrict__ wbias,
    const float* __restrict__ mask,
    float* __restrict__ pb)
{
    __shared__ float S[8][1032];
    __shared__ float maskS[1024];
    const int t = threadIdx.x;
    const int bi = blockIdx.x;       // b*1024 + i
    const int b = bi >> 10, i = bi & 1023;
    const int l = t & 15, grp = t >> 4;

    // per-lane constants (channels 4l..4l+3)
    float wg[4], wb_[4];
    fv4 w0[4], w1[4];
    #pragma unroll
    for (int cc=0; cc<4; ++cc){
        const int c = 4*l + cc;
        wg[cc] = lnzg[c]; wb_[cc] = lnzb[c];
        w0[cc] = *(const fv4*)&wbias[c*8];
        w1[cc] = *(const fv4*)&wbias[c*8+4];
    }
    *(fv4*)&maskS[t*4] = ((const fv4*)(mask + (b<<10)))[t];
    __syncthreads();
    const float mi = mask[bi];

    const fv4* fpv = (const fv4*)(fp + (size_t)bi*65536);
    fv4 cur = fpv[(size_t)grp*16 + l];
    #pragma unroll 1
    for (int jt=0; jt<1024; jt+=16){
        const int j = jt + grp;
        const fv4 f = cur;
        if (jt+16 < 1024) cur = fpv[(size_t)(j+16)*16 + l];
        // LN stats over 64 channels (one-pass: var = E[x^2]-mu^2)
        float s1 = f.x+f.y+f.z+f.w;
        float s2 = f.x*f.x+f.y*f.y+f.z*f.z+f.w*f.w;
        #pragma unroll
        for (int m=1;m<16;m<<=1){ s1 += __shfl_xor(s1,m); s2 += __shfl_xor(s2,m); }
        const float mu = s1*(1.f/64.f);
        const float rs = rsqrtf(s2*(1.f/64.f) - mu*mu + 1e-5f);
        float lnv[4];
        lnv[0]=(f.x-mu)*rs*wg[0]+wb_[0];
        lnv[1]=(f.y-mu)*rs*wg[1]+wb_[1];
        lnv[2]=(f.z-mu)*rs*wg[2]+wb_[2];
        lnv[3]=(f.w-mu)*rs*wg[3]+wb_[3];
        float pv[8] = {};
        #pragma unroll
        for (int cc=0;cc<4;++cc){
            pv[0]+=lnv[cc]*w0[cc].x; pv[1]+=lnv[cc]*w0[cc].y;
            pv[2]+=lnv[cc]*w0[cc].z; pv[3]+=lnv[cc]*w0[cc].w;
            pv[4]+=lnv[cc]*w1[cc].x; pv[5]+=lnv[cc]*w1[cc].y;
            pv[6]+=lnv[cc]*w1[cc].z; pv[7]+=lnv[cc]*w1[cc].w;
        }
        // reduce-scatter over 16 lanes: after steps 8/4/2 lane holds
        // h = (l>>1)&7 partials over its 2-lane pair; step 1 finishes.
        {
            const bool b8 = (l & 8);
            #pragma unroll
            for (int k=0;k<4;++k){
                const float a = b8 ? pv[k] : pv[k+4];
                const float r = __shfl_xor(a, 8);
                pv[k] = (b8 ? pv[k+4] : pv[k]) + r;
            }
            const bool b4 = (l & 4);
            #pragma unroll
            for (int k=0;k<2;++k){
                const float a = b4 ? pv[k] : pv[k+2];
                const float r = __shfl_xor(a, 4);
                pv[k] = (b4 ? pv[k+2] : pv[k]) + r;
            }
            const bool b2 = (l & 2);
            {
                const float a = b2 ? pv[0] : pv[1];
                const float r = __shfl_xor(a, 2);
                pv[0] = (b2 ? pv[1] : pv[0]) + r;
            }
            pv[0] += __shfl_xor(pv[0], 1);
        }
        if ((l & 1) == 0){
            const float mterm = (mi*maskS[j]-1.f)*100000.f;
            S[(l>>1)][j] = pv[0] + mterm;
        }
    }
    __syncthreads();
    // write-out: 1KB contiguous per wave instruction (fv4 per lane)
    #pragma unroll 1
    for (int k=0;k<8;++k){
        const int idx = k*256 + t;         // plane k
        const int j4 = (idx & 255) * 4;
        const fv4 v = *(const fv4*)&S[k][j4];
        *(fv4*)&pb[(((size_t)(b*8+k))*1024 + i)*1024 + j4] = v;
    }
}

// ---- attention: 8 query rows x 1 head per block; no barriers needed ------
// Each 32-lane group owns one query row end-to-end (QK^T, softmax, PV).
__global__ __launch_bounds__(256,4) void attn_tile(
    const float* __restrict__ qkvg,
    const float* __restrict__ kT,
    const float* __restrict__ pb,
    float* __restrict__ og)
{
    __shared__ float S[8][1032];
    __shared__ float qs[8][33];
    __shared__ float denomS[8];
    const int t = threadIdx.x;
    const int it = blockIdx.x;       // i-tile (8 rows) within batch
    const int h  = blockIdx.y;
    const int b  = blockIdx.z;
    const int i0 = it*8;
    const int r = t >> 5, jl = t & 31;
    qs[r][jl] = qkvg[((size_t)(b*1024 + i0 + r))*1024 + h*32 + jl];
    float q[32];
    #pragma unroll
    for (int d=0; d<32; ++d) q[d] = qs[r][d];

    const float scale = 0.17677669529663687f; // 1/sqrt(32)
    const float* kTb = kT + ((size_t)b*256 + h*32)*1024;
    const float* pbr = pb + (((size_t)(b*8+h))*1024 + i0 + r)*1024;
    for (int jt=0; jt<1024; jt+=64){
        const int j0 = jt + jl*2;
        float a0=0.f, a1=0.f;
        #pragma unroll
        for (int d=0; d<32; ++d){
            const float2 k2 = *(const float2*)(kTb + (size_t)d*1024 + j0);
            a0 += q[d]*k2.x; a1 += q[d]*k2.y;
        }
        const float2 pb2 = *(const float2*)(pbr + j0);
        S[r][j0]   = a0*scale + pb2.x;
        S[r][j0+1] = a1*scale + pb2.y;
    }
    {
        float mx = -3.4e38f;
        for (int jj=jl; jj<1024; jj+=32) mx = fmaxf(mx, S[r][jj]);
        #pragma unroll
        for (int off=16; off>0; off>>=1) mx = fmaxf(mx, __shfl_xor(mx, off, 32));
        float sum = 0.f;
        for (int jj=jl; jj<1024; jj+=32){
            const float e = __expf(S[r][jj]-mx);
            S[r][jj] = e;
            sum += e;
        }
        #pragma unroll
        for (int off=16; off>0; off>>=1) sum += __shfl_xor(sum, off, 32);
        if (jl==0) denomS[r] = sum;
    }
    float o = 0.f;
    const float* vcol = qkvg + ((size_t)(b*1024))*1024 + 512 + h*32 + jl;
    #pragma unroll 2
    for (int j=0; j<1024; j+=4){
        const float4 p = *(const float4*)&S[r][j];
        const float v0 = vcol[(size_t)(j+0)*1024];
        const float v1 = vcol[(size_t)(j+1)*1024];
        const float v2 = vcol[(size_t)(j+2)*1024];
        const float v3 = vcol[(size_t)(j+3)*1024];
        o += p.x*v0 + p.y*v1 + p.z*v2 + p.w*v3;
    }
    const int row = b*1024 + i0 + r;
    const float gpre = qkvg[(size_t)row*1024 + 768 + h*32 + jl];
    og[(size_t)row*256 + h*32 + jl] = (o/denomS[r]) * sigm(gpre);
}

// ---- sa = LN(rig)*sigmoid(cond_gate) + cond_bias -------------------------
__global__ __launch_bounds__(256) void sa_kernel(
    const float* __restrict__ rig,
    const float* __restrict__ c1res,
    const float* __restrict__ cbres,
    const int* __restrict__ idxp,
    const float* __restrict__ mask,
    float* __restrict__ sa)
{
    __shared__ float red[16];
    const int m = blockIdx.x;
    const int t = threadIdx.x;
    const float v = rig[(size_t)m*256 + t];
    float s1 = v, s2 = v*v;
    blockReduce2(s1,s2,red);
    const float mu = s1*(1.f/256.f);
    const float rs = rsqrtf(s2*(1.f/256.f) - mu*mu + 1e-5f);
    const float sn = (v-mu)*rs;
    const float mi = mask[m];
    const int id = idxp[m];
    const int b = m >> 10;
    const size_t go = ((size_t)(b*256+id))*256 + t;
    const float cgate = c1res[go]*mi;
    const float cb    = cbres[go]*mi;
    sa[(size_t)m*256+t] = sn*sigm(cgate) + cb;
}

extern "C" void kernel_launch(void* const* d_in, const int* in_sizes, int n_in,
                              void* d_out, int out_size, void* d_ws, size_t ws_size,
                              hipStream_t stream)
{
    (void)in_sizes; (void)n_in; (void)out_size; (void)ws_size;
    const float* s_     = (const float*)d_in[0];
    const float* rigids = (const float*)d_in[1];
    const float* fp     = (const float*)d_in[2];
    const float* maskp  = (const float*)d_in[3];
    const int*   idxp   = (const int*)d_in[4];
    const float* ln_g   = (const float*)d_in[5];
    const float* ln_b   = (const float*)d_in[6];
    const float* Wq     = (const float*)d_in[7];
    const float* Wkv    = (const float*)d_in[8];
    const float* lnz_g  = (const float*)d_in[9];
    const float* lnz_b  = (const float*)d_in[10];
    const float* Wbias  = (const float*)d_in[11];
    const float* Wg     = (const float*)d_in[12];
    const float* Wo     = (const float*)d_in[13];
    const float* lncond = (const float*)d_in[14];
    const float* Wc1    = (const float*)d_in[15];
    const float* bc1    = (const float*)d_in[16];
    const float* Wcn    = (const float*)d_in[17];
    const float* W1     = (const float*)d_in[18];
    const float* W2     = (const float*)d_in[19];
    const float* Wc2    = (const float*)d_in[20];
    const float* bc2    = (const float*)d_in[21];
    const float* Wb     = (const float*)d_in[22];
    float* out = (float*)d_out;

    float* ws    = (float*)d_ws;
    float* x     = ws;                  // 2048*256
    float* qkvg  = x     + 524288;      // 2048*1024
    float* ogb   = qkvg  + 2097152;     // 2048*256
    float* rig   = ogb   + 524288;      // 2048*256
    float* cn    = rig   + 524288;      // 512*384
    float* c1res = cn    + 196608;      // 512*256
    float* cbres = c1res + 131072;      // 512*256
    float* cgres = cbres + 131072;      // 512*256
    float* sab   = cgres + 131072;      // 2048*256
    float* bmid  = sab   + 524288;      // 2048*512
    float* kT    = bmid  + 1048576;     // 2*256*1024
    float* pbuf  = kT    + 524288;      // 2*8*1024*1024 = 64 MB

    pb_kernel<<<2048,256,0,stream>>>(fp, lnz_g, lnz_b, Wbias, maskp, pbuf);
    ln_rows<<<2048,256,0,stream>>>(rigids, ln_g, ln_b, x, 256);
    gemm_t<0><<<dim3(32,4),256,0,stream>>>(x,256, Wq,256,  qkvg,     1024, 2048,256,256, nullptr,nullptr,nullptr,nullptr,nullptr);
    gemm_t<0><<<dim3(32,8),256,0,stream>>>(x,256, Wkv,512, qkvg+256, 1024, 2048,512,256, nullptr,nullptr,nullptr,nullptr,nullptr);
    gemm_t<0><<<dim3(32,4),256,0,stream>>>(x,256, Wg,256,  qkvg+768, 1024, 2048,256,256, nullptr,nullptr,nullptr,nullptr,nullptr);
    ktrans<<<dim3(16,4,2),256,0,stream>>>(qkvg, kT);
    attn_tile<<<dim3(128,8,2),256,0,stream>>>(qkvg, kT, pbuf, ogb);
    gemm_t<1><<<dim3(32,4),256,0,stream>>>(ogb,256, Wo,256, rig,256, 2048,256,256, nullptr, rigids, maskp, nullptr,nullptr);
    ln_rows<<<512,256,0,stream>>>(s_, lncond, nullptr, cn, 384);
    gemm_t<0><<<dim3(8,4),256,0,stream>>>(cn,384, Wc1,256, c1res,256, 512,256,384, bc1,    nullptr,nullptr,nullptr,nullptr);
    gemm_t<0><<<dim3(8,4),256,0,stream>>>(cn,384, Wcn,256, cbres,256, 512,256,384, nullptr,nullptr,nullptr,nullptr,nullptr);
    gemm_t<0><<<dim3(8,4),256,0,stream>>>(s_,384, Wc2,256, cgres,256, 512,256,384, bc2,    nullptr,nullptr,nullptr,nullptr);
    sa_kernel<<<2048,256,0,stream>>>(rig, c1res, cbres, idxp, maskp, sab);
    gemm_dual<<<dim3(32,8),256,0,stream>>>(sab,256, W1, W2, 512, bmid,512, 2048,512,256);
    gemm_t<2><<<dim3(32,4),256,0,stream>>>(bmid,512, Wb,256, out,256, 2048,256,512, nullptr, rig, maskp, cgres, idxp);
}

// Round 7
// 587.585 us; speedup vs baseline: 1.7800x; 1.0322x over previous
//
#include <hip/hip_runtime.h>
#include <math.h>

#define DEVI __device__ __forceinline__
typedef float fv4 __attribute__((ext_vector_type(4)));

DEVI float sigm(float x){ return 1.f/(1.f+__expf(-x)); }

// ---- block-wide (256 thr) reduction of two sums --------------------------
DEVI void blockReduce2(float& s1, float& s2, float* red){
    #pragma unroll
    for (int m=1;m<64;m<<=1){ s1+=__shfl_xor(s1,m); s2+=__shfl_xor(s2,m); }
    const int w = threadIdx.x>>6;
    if ((threadIdx.x&63)==0){ red[w]=s1; red[8+w]=s2; }
    __syncthreads();
    s1 = red[0]+red[1]+red[2]+red[3];
    s2 = red[8]+red[9]+red[10]+red[11];
}

// ---- generic row LayerNorm ----------------------------------------------
__global__ __launch_bounds__(256) void ln_rows(const float* __restrict__ in,
                                               const float* __restrict__ g,
                                               const float* __restrict__ bt,
                                               float* __restrict__ out, int C){
    __shared__ float red[16];
    const size_t row = blockIdx.x;
    const float* x = in + row*(size_t)C;
    float s1=0.f, s2=0.f;
    for (int c=threadIdx.x; c<C; c+=256){ float v=x[c]; s1+=v; s2+=v*v; }
    blockReduce2(s1,s2,red);
    const float inv = 1.f/(float)C;
    const float mu = s1*inv;
    const float rs = rsqrtf(s2*inv - mu*mu + 1e-5f);
    float* o = out + row*(size_t)C;
    for (int c=threadIdx.x; c<C; c+=256){
        float y = (x[c]-mu)*rs;
        if (g)  y *= g[c];
        if (bt) y += bt[c];
        o[c] = y;
    }
}

// ---- concat [Wq | Wkv | Wg] into wcat[256][1024] --------------------------
__global__ __launch_bounds__(256) void concat_w(const float* __restrict__ Wq,
                                                const float* __restrict__ Wkv,
                                                const float* __restrict__ Wg,
                                                float* __restrict__ wcat){
    const int k = blockIdx.x;        // 0..255
    const int t = threadIdx.x;       // 0..255
    wcat[(size_t)k*1024 + t]       = Wq [(size_t)k*256 + t];
    wcat[(size_t)k*1024 + 256 + t] = Wkv[(size_t)k*512 + t];
    wcat[(size_t)k*1024 + 512 + t] = Wkv[(size_t)k*512 + 256 + t];
    wcat[(size_t)k*1024 + 768 + t] = Wg [(size_t)k*256 + t];
}

// ---- K/V transpose: kT/vT[b][d][j] from qkvg ------------------------------
__global__ __launch_bounds__(256) void kvtrans(const float* __restrict__ qkvg,
                                               float* __restrict__ kT,
                                               float* __restrict__ vT){
    __shared__ float tile[64][65];
    const int t = threadIdx.x;
    const int jt = blockIdx.x*64, dt = blockIdx.y*64, b = blockIdx.z;
    const int c = t & 63, r0 = t >> 6;
    #pragma unroll 4
    for (int rr=r0; rr<64; rr+=4)
        tile[rr][c] = qkvg[(size_t)((b<<10)+jt+rr)*1024 + 256 + dt + c];
    __syncthreads();
    #pragma unroll 4
    for (int rr=r0; rr<64; rr+=4)
        kT[((size_t)(b*256 + dt + rr))*1024 + jt + c] = tile[c][rr];
    __syncthreads();
    #pragma unroll 4
    for (int rr=r0; rr<64; rr+=4)
        tile[rr][c] = qkvg[(size_t)((b<<10)+jt+rr)*1024 + 512 + dt + c];
    __syncthreads();
    #pragma unroll 4
    for (int rr=r0; rr<64; rr+=4)
        vT[((size_t)(b*256 + dt + rr))*1024 + jt + c] = tile[c][rr];
}

// ---- tiled f32 GEMM: C(MxN) = A(MxK) @ B(KxN), 64x64 tile, BK=16 --------
// MODE 0: C = A@B (+bias)          MODE 1: C = resid + (A@B)*mask[m]
// MODE 2: C = resid + sigmoid(gather*mask)*(A@B)*mask[m]
template<int MODE>
__global__ __launch_bounds__(256) void gemm_t(
    const float* __restrict__ A, int lda,
    const float* __restrict__ B, int ldb,
    float* __restrict__ C, int ldc,
    int M, int N, int K,
    const float* __restrict__ bias,
    const float* __restrict__ resid,
    const float* __restrict__ mask,
    const float* __restrict__ gsrc,
    const int* __restrict__ idxp)
{
    __shared__ float As[16][68];
    __shared__ float Bs[16][68];
    const int t = threadIdx.x;
    const int tx = t & 15, ty = t >> 4;
    const int bm = blockIdx.x * 64, bn = blockIdx.y * 64;
    const int am = t >> 2, akq = (t & 3) * 4;
    const int bk = t >> 4, bnq = (t & 15) * 4;
    float acc[4][4] = {};
    for (int kt = 0; kt < K; kt += 16) {
        const float4 va = *(const float4*)&A[(size_t)(bm+am)*lda + kt + akq];
        const float4 vb = *(const float4*)&B[(size_t)(kt+bk)*ldb + bn + bnq];
        As[akq+0][am]=va.x; As[akq+1][am]=va.y; As[akq+2][am]=va.z; As[akq+3][am]=va.w;
        *(float4*)&Bs[bk][bnq] = vb;
        __syncthreads();
        #pragma unroll
        for (int kk=0; kk<16; ++kk){
            const float4 af = *(const float4*)&As[kk][ty*4];
            const float4 bf = *(const float4*)&Bs[kk][tx*4];
            acc[0][0]+=af.x*bf.x; acc[0][1]+=af.x*bf.y; acc[0][2]+=af.x*bf.z; acc[0][3]+=af.x*bf.w;
            acc[1][0]+=af.y*bf.x; acc[1][1]+=af.y*bf.y; acc[1][2]+=af.y*bf.z; acc[1][3]+=af.y*bf.w;
            acc[2][0]+=af.z*bf.x; acc[2][1]+=af.z*bf.y; acc[2][2]+=af.z*bf.z; acc[2][3]+=af.z*bf.w;
            acc[3][0]+=af.w*bf.x; acc[3][1]+=af.w*bf.y; acc[3][2]+=af.w*bf.z; acc[3][3]+=af.w*bf.w;
        }
        __syncthreads();
    }
    #pragma unroll
    for (int i=0;i<4;++i){
        const int m = bm + ty*4 + i;
        #pragma unroll
        for (int jj=0;jj<4;++jj){
            const int n = bn + tx*4 + jj;
            float v = acc[i][jj];
            if (MODE==0){
                if (bias) v += bias[n];
                C[(size_t)m*ldc+n] = v;
            } else if (MODE==1){
                const float mi = mask[m];
                C[(size_t)m*ldc+n] = resid[(size_t)m*256+n] + v*mi;
            } else {
                const float mi = mask[m];
                const int id = idxp[m];
                const int bbi = m >> 10;
                const float cg = gsrc[((size_t)(bbi*256+id))*256 + n]*mi;
                C[(size_t)m*ldc+n] = resid[(size_t)m*256+n] + sigm(cg)*v*mi;
            }
        }
    }
}

// ---- dual-B GEMM: bmid = silu(A@B1) * (A@B2) ----------------------------
__global__ __launch_bounds__(256) void gemm_dual(
    const float* __restrict__ A, int lda,
    const float* __restrict__ B1, const float* __restrict__ B2, int ldb,
    float* __restrict__ C, int ldc,
    int M, int N, int K)
{
    __shared__ float As[16][68];
    __shared__ float B1s[16][68];
    __shared__ float B2s[16][68];
    const int t = threadIdx.x;
    const int tx = t & 15, ty = t >> 4;
    const int bm = blockIdx.x * 64, bn = blockIdx.y * 64;
    const int am = t >> 2, akq = (t & 3) * 4;
    const int bk = t >> 4, bnq = (t & 15) * 4;
    float acc1[4][4] = {};
    float acc2[4][4] = {};
    for (int kt = 0; kt < K; kt += 16) {
        const float4 va  = *(const float4*)&A [(size_t)(bm+am)*lda + kt + akq];
        const float4 vb1 = *(const float4*)&B1[(size_t)(kt+bk)*ldb + bn + bnq];
        const float4 vb2 = *(const float4*)&B2[(size_t)(kt+bk)*ldb + bn + bnq];
        As[akq+0][am]=va.x; As[akq+1][am]=va.y; As[akq+2][am]=va.z; As[akq+3][am]=va.w;
        *(float4*)&B1s[bk][bnq] = vb1;
        *(float4*)&B2s[bk][bnq] = vb2;
        __syncthreads();
        #pragma unroll
        for (int kk=0; kk<16; ++kk){
            const float4 af = *(const float4*)&As[kk][ty*4];
            const float4 b1 = *(const float4*)&B1s[kk][tx*4];
            const float4 b2 = *(const float4*)&B2s[kk][tx*4];
            acc1[0][0]+=af.x*b1.x; acc1[0][1]+=af.x*b1.y; acc1[0][2]+=af.x*b1.z; acc1[0][3]+=af.x*b1.w;
            acc1[1][0]+=af.y*b1.x; acc1[1][1]+=af.y*b1.y; acc1[1][2]+=af.y*b1.z; acc1[1][3]+=af.y*b1.w;
            acc1[2][0]+=af.z*b1.x; acc1[2][1]+=af.z*b1.y; acc1[2][2]+=af.z*b1.z; acc1[2][3]+=af.z*b1.w;
            acc1[3][0]+=af.w*b1.x; acc1[3][1]+=af.w*b1.y; acc1[3][2]+=af.w*b1.z; acc1[3][3]+=af.w*b1.w;
            acc2[0][0]+=af.x*b2.x; acc2[0][1]+=af.x*b2.y; acc2[0][2]+=af.x*b2.z; acc2[0][3]+=af.x*b2.w;
            acc2[1][0]+=af.y*b2.x; acc2[1][1]+=af.y*b2.y; acc2[1][2]+=af.y*b2.z; acc2[1][3]+=af.y*b2.w;
            acc2[2][0]+=af.z*b2.x; acc2[2][1]+=af.z*b2.y; acc2[2][2]+=af.z*b2.z; acc2[2][3]+=af.z*b2.w;
            acc2[3][0]+=af.w*b2.x; acc2[3][1]+=af.w*b2.y; acc2[3][2]+=af.w*b2.z; acc2[3][3]+=af.w*b2.w;
        }
        __syncthreads();
    }
    #pragma unroll
    for (int i=0;i<4;++i){
        const int m = bm + ty*4 + i;
        #pragma unroll
        for (int jj=0;jj<4;++jj){
            const int n = bn + tx*4 + jj;
            const float u1 = acc1[i][jj];
            C[(size_t)m*ldc+n] = u1*sigm(u1)*acc2[i][jj];
        }
    }
}

// ---- pair-bias precompute: pb[b][h][i][j] = LN(fp)@Wbias + maskterm ------
// 16-lane groups; every wave load/store instruction covers 1KB CONTIGUOUS.
__global__ __launch_bounds__(256,4) void pb_kernel(
    const float* __restrict__ fp,
    const float* __restrict__ lnzg, const float* __restrict__ lnzb,
    const float* __restrict__ wbias,
    const float* __restrict__ mask,
    float* __restrict__ pb)
{
    __shared__ float S[8][1032];
    __shared__ float maskS[1024];
    const int t = threadIdx.x;
    const int bi = blockIdx.x;       // b*1024 + i
    const int b = bi >> 10, i = bi & 1023;
    const int l = t & 15, grp = t >> 4;

    float wg[4], wb_[4];
    fv4 w0[4], w1[4];
    #pragma unroll
    for (int cc=0; cc<4; ++cc){
        const int c = 4*l + cc;
        wg[cc] = lnzg[c]; wb_[cc] = lnzb[c];
        w0[cc] = *(const fv4*)&wbias[c*8];
        w1[cc] = *(const fv4*)&wbias[c*8+4];
    }
    *(fv4*)&maskS[t*4] = ((const fv4*)(mask + (b<<10)))[t];
    __syncthreads();
    const float mi = mask[bi];

    const fv4* fpv = (const fv4*)(fp + (size_t)bi*65536);
    fv4 cur = fpv[(size_t)grp*16 + l];
    #pragma unroll 1
    for (int jt=0; jt<1024; jt+=16){
        const int j = jt + grp;
        const fv4 f = cur;
        if (jt+16 < 1024) cur = fpv[(size_t)(j+16)*16 + l];
        float s1 = f.x+f.y+f.z+f.w;
        float s2 = f.x*f.x+f.y*f.y+f.z*f.z+f.w*f.w;
        #pragma unroll
        for (int m=1;m<16;m<<=1){ s1 += __shfl_xor(s1,m); s2 += __shfl_xor(s2,m); }
        const float mu = s1*(1.f/64.f);
        const float rs = rsqrtf(s2*(1.f/64.f) - mu*mu + 1e-5f);
        float lnv[4];
        lnv[0]=(f.x-mu)*rs*wg[0]+wb_[0];
        lnv[1]=(f.y-mu)*rs*wg[1]+wb_[1];
        lnv[2]=(f.z-mu)*rs*wg[2]+wb_[2];
        lnv[3]=(f.w-mu)*rs*wg[3]+wb_[3];
        float pv[8] = {};
        #pragma unroll
        for (int cc=0;cc<4;++cc){
            pv[0]+=lnv[cc]*w0[cc].x; pv[1]+=lnv[cc]*w0[cc].y;
            pv[2]+=lnv[cc]*w0[cc].z; pv[3]+=lnv[cc]*w0[cc].w;
            pv[4]+=lnv[cc]*w1[cc].x; pv[5]+=lnv[cc]*w1[cc].y;
            pv[6]+=lnv[cc]*w1[cc].z; pv[7]+=lnv[cc]*w1[cc].w;
        }
        {
            const bool b8 = (l & 8);
            #pragma unroll
            for (int k=0;k<4;++k){
                const float a = b8 ? pv[k] : pv[k+4];
                const float r = __shfl_xor(a, 8);
                pv[k] = (b8 ? pv[k+4] : pv[k]) + r;
            }
            const bool b4 = (l & 4);
            #pragma unroll
            for (int k=0;k<2;++k){
                const float a = b4 ? pv[k] : pv[k+2];
                const float r = __shfl_xor(a, 4);
                pv[k] = (b4 ? pv[k+2] : pv[k]) + r;
            }
            const bool b2 = (l & 2);
            {
                const float a = b2 ? pv[0] : pv[1];
                const float r = __shfl_xor(a, 2);
                pv[0] = (b2 ? pv[1] : pv[0]) + r;
            }
            pv[0] += __shfl_xor(pv[0], 1);
        }
        if ((l & 1) == 0){
            const float mterm = (mi*maskS[j]-1.f)*100000.f;
            S[(l>>1)][j] = pv[0] + mterm;
        }
    }
    __syncthreads();
    #pragma unroll 1
    for (int k=0;k<8;++k){
        const int j4 = (t & 255) * 4;
        const fv4 v = *(const fv4*)&S[k][j4];
        *(fv4*)&pb[(((size_t)(b*8+k))*1024 + i)*1024 + j4] = v;
    }
}

// ---- attention: 8 query rows x 1 head per block ---------------------------
// QK^T via kT (coalesced); PV via vT: lane jl accumulates all 32 d over its
// j-slice (contiguous fv4 loads), then 5-step shfl reduce-scatter leaves
// lane jl holding o[d=jl]. No syncthreads needed between groups.
__global__ __launch_bounds__(256,4) void attn_tile(
    const float* __restrict__ qkvg,
    const float* __restrict__ kT,
    const float* __restrict__ vT,
    const float* __restrict__ pb,
    float* __restrict__ og)
{
    __shared__ float S[8][1032];
    __shared__ float qs[8][33];
    __shared__ float denomS[8];
    const int t = threadIdx.x;
    const int it = blockIdx.x;       // i-tile (8 rows) within batch
    const int h  = blockIdx.y;
    const int b  = blockIdx.z;
    const int i0 = it*8;
    const int r = t >> 5, jl = t & 31;
    qs[r][jl] = qkvg[((size_t)(b*1024 + i0 + r))*1024 + h*32 + jl];
    float q[32];
    #pragma unroll
    for (int d=0; d<32; ++d) q[d] = qs[r][d];

    const float scale = 0.17677669529663687f; // 1/sqrt(32)
    const float* kTb = kT + ((size_t)b*256 + h*32)*1024;
    const float* pbr = pb + (((size_t)(b*8+h))*1024 + i0 + r)*1024;
    for (int jt=0; jt<1024; jt+=64){
        const int j0 = jt + jl*2;
        float a0=0.f, a1=0.f;
        #pragma unroll
        for (int d=0; d<32; ++d){
            const float2 k2 = *(const float2*)(kTb + (size_t)d*1024 + j0);
            a0 += q[d]*k2.x; a1 += q[d]*k2.y;
        }
        const float2 pb2 = *(const float2*)(pbr + j0);
        S[r][j0]   = a0*scale + pb2.x;
        S[r][j0+1] = a1*scale + pb2.y;
    }
    // softmax over the row (32-lane group)
    {
        float mx = -3.4e38f;
        for (int jj=jl; jj<1024; jj+=32) mx = fmaxf(mx, S[r][jj]);
        #pragma unroll
        for (int off=16; off>0; off>>=1) mx = fmaxf(mx, __shfl_xor(mx, off, 32));
        float sum = 0.f;
        for (int jj=jl; jj<1024; jj+=32){
            const float e = __expf(S[r][jj]-mx);
            S[r][jj] = e;
            sum += e;
        }
        #pragma unroll
        for (int off=16; off>0; off>>=1) sum += __shfl_xor(sum, off, 32);
        if (jl==0) denomS[r] = sum;
    }
    // PV: lane jl accumulates partial o[d] for all d over j in {jl*4+128k}
    float acc[32];
    const float* vTb = vT + ((size_t)b*256 + h*32)*1024;
    #pragma unroll
    for (int d=0; d<32; ++d){
        const fv4* vrow4 = (const fv4*)(vTb + (size_t)d*1024);
        float a0 = 0.f;
        #pragma unroll
        for (int k=0;k<8;++k){
            const fv4 vv = vrow4[k*32 + jl];
            const fv4 pp = *(const fv4*)&S[r][(k*32 + jl)*4];
            a0 += pp.x*vv.x + pp.y*vv.y + pp.z*vv.z + pp.w*vv.w;
        }
        acc[d] = a0;
    }
    // reduce-scatter across 32 lanes -> lane jl holds o[d=jl]
    {
        const bool c16 = jl & 16;
        #pragma unroll
        for (int k=0;k<16;++k){
            const float a = c16 ? acc[k] : acc[k+16];
            const float rr = __shfl_xor(a, 16);
            acc[k] = (c16 ? acc[k+16] : acc[k]) + rr;
        }
        const bool c8 = jl & 8;
        #pragma unroll
        for (int k=0;k<8;++k){
            const float a = c8 ? acc[k] : acc[k+8];
            const float rr = __shfl_xor(a, 8);
            acc[k] = (c8 ? acc[k+8] : acc[k]) + rr;
        }
        const bool c4 = jl & 4;
        #pragma unroll
        for (int k=0;k<4;++k){
            const float a = c4 ? acc[k] : acc[k+4];
            const float rr = __shfl_xor(a, 4);
            acc[k] = (c4 ? acc[k+4] : acc[k]) + rr;
        }
        const bool c2 = jl & 2;
        #pragma unroll
        for (int k=0;k<2;++k){
            const float a = c2 ? acc[k] : acc[k+2];
            const float rr = __shfl_xor(a, 2);
            acc[k] = (c2 ? acc[k+2] : acc[k]) + rr;
        }
        const bool c1 = jl & 1;
        {
            const float a = c1 ? acc[0] : acc[1];
            const float rr = __shfl_xor(a, 1);
            acc[0] = (c1 ? acc[1] : acc[0]) + rr;
        }
    }
    const int row = b*1024 + i0 + r;
    const float gpre = qkvg[(size_t)row*1024 + 768 + h*32 + jl];
    og[(size_t)row*256 + h*32 + jl] = (acc[0]/denomS[r]) * sigm(gpre);
}

// ---- sa = LN(rig)*sigmoid(cond_gate) + cond_bias -------------------------
__global__ __launch_bounds__(256) void sa_kernel(
    const float* __restrict__ rig,
    const float* __restrict__ c1res,
    const float* __restrict__ cbres,
    const int* __restrict__ idxp,
    const float* __restrict__ mask,
    float* __restrict__ sa)
{
    __shared__ float red[16];
    const int m = blockIdx.x;
    const int t = threadIdx.x;
    const float v = rig[(size_t)m*256 + t];
    float s1 = v, s2 = v*v;
    blockReduce2(s1,s2,red);
    const float mu = s1*(1.f/256.f);
    const float rs = rsqrtf(s2*(1.f/256.f) - mu*mu + 1e-5f);
    const float sn = (v-mu)*rs;
    const float mi = mask[m];
    const int id = idxp[m];
    const int b = m >> 10;
    const size_t go = ((size_t)(b*256+id))*256 + t;
    const float cgate = c1res[go]*mi;
    const float cb    = cbres[go]*mi;
    sa[(size_t)m*256+t] = sn*sigm(cgate) + cb;
}

extern "C" void kernel_launch(void* const* d_in, const int* in_sizes, int n_in,
                              void* d_out, int out_size, void* d_ws, size_t ws_size,
                              hipStream_t stream)
{
    (void)in_sizes; (void)n_in; (void)out_size; (void)ws_size;
    const float* s_     = (const float*)d_in[0];
    const float* rigids = (const float*)d_in[1];
    const float* fp     = (const float*)d_in[2];
    const float* maskp  = (const float*)d_in[3];
    const int*   idxp   = (const int*)d_in[4];
    const float* ln_g   = (const float*)d_in[5];
    const float* ln_b   = (const float*)d_in[6];
    const float* Wq     = (const float*)d_in[7];
    const float* Wkv    = (const float*)d_in[8];
    const float* lnz_g  = (const float*)d_in[9];
    const float* lnz_b  = (const float*)d_in[10];
    const float* Wbias  = (const float*)d_in[11];
    const float* Wg     = (const float*)d_in[12];
    const float* Wo     = (const float*)d_in[13];
    const float* lncond = (const float*)d_in[14];
    const float* Wc1    = (const float*)d_in[15];
    const float* bc1    = (const float*)d_in[16];
    const float* Wcn    = (const float*)d_in[17];
    const float* W1     = (const float*)d_in[18];
    const float* W2     = (const float*)d_in[19];
    const float* Wc2    = (const float*)d_in[20];
    const float* bc2    = (const float*)d_in[21];
    const float* Wb     = (const float*)d_in[22];
    float* out = (float*)d_out;

    float* ws    = (float*)d_ws;
    float* x     = ws;                  // 2048*256
    float* qkvg  = x     + 524288;      // 2048*1024
    float* ogb   = qkvg  + 2097152;     // 2048*256
    float* rig   = ogb   + 524288;      // 2048*256
    float* cn    = rig   + 524288;      // 512*384
    float* c1res = cn    + 196608;      // 512*256
    float* cbres = c1res + 131072;      // 512*256
    float* cgres = cbres + 131072;      // 512*256
    float* sab   = cgres + 131072;      // 2048*256
    float* bmid  = sab   + 524288;      // 2048*512
    float* kT    = bmid  + 1048576;     // 2*256*1024
    float* vT    = kT    + 524288;      // 2*256*1024
    float* wcat  = vT    + 524288;      // 256*1024
    float* pbuf  = wcat  + 262144;      // 2*8*1024*1024 = 64 MB

    pb_kernel<<<2048,256,0,stream>>>(fp, lnz_g, lnz_b, Wbias, maskp, pbuf);
    concat_w<<<256,256,0,stream>>>(Wq, Wkv, Wg, wcat);
    ln_rows<<<2048,256,0,stream>>>(rigids, ln_g, ln_b, x, 256);
    gemm_t<0><<<dim3(32,16),256,0,stream>>>(x,256, wcat,1024, qkvg,1024, 2048,1024,256, nullptr,nullptr,nullptr,nullptr,nullptr);
    kvtrans<<<dim3(16,4,2),256,0,stream>>>(qkvg, kT, vT);
    attn_tile<<<dim3(128,8,2),256,0,stream>>>(qkvg, kT, vT, pbuf, ogb);
    gemm_t<1><<<dim3(32,4),256,0,stream>>>(ogb,256, Wo,256, rig,256, 2048,256,256, nullptr, rigids, maskp, nullptr,nullptr);
    ln_rows<<<512,256,0,stream>>>(s_, lncond, nullptr, cn, 384);
    gemm_t<0><<<dim3(8,4),256,0,stream>>>(cn,384, Wc1,256, c1res,256, 512,256,384, bc1,    nullptr,nullptr,nullptr,nullptr);
    gemm_t<0><<<dim3(8,4),256,0,stream>>>(cn,384, Wcn,256, cbres,256, 512,256,384, nullptr,nullptr,nullptr,nullptr,nullptr);
    gemm_t<0><<<dim3(8,4),256,0,stream>>>(s_,384, Wc2,256, cgres,256, 512,256,384, bc2,    nullptr,nullptr,nullptr,nullptr);
    sa_kernel<<<2048,256,0,stream>>>(rig, c1res, cbres, idxp, maskp, sab);
    gemm_dual<<<dim3(32,8),256,0,stream>>>(sab,256, W1, W2, 512, bmid,512, 2048,512,256);
    gemm_t<2><<<dim3(32,4),256,0,stream>>>(bmid,512, Wb,256, out,256, 2048,256,512, nullptr, rig, maskp, cgres, idxp);
}

// Round 8
// 532.523 us; speedup vs baseline: 1.9640x; 1.1034x over previous
//
#include <hip/hip_runtime.h>
#include <math.h>

#define DEVI __device__ __forceinline__
typedef float fv4 __attribute__((ext_vector_type(4)));
typedef float f32x4 __attribute__((ext_vector_type(4)));
typedef short bf16x8 __attribute__((ext_vector_type(8)));

DEVI float sigm(float x){ return 1.f/(1.f+__expf(-x)); }
DEVI unsigned short f2bf(float f){
    unsigned int u = __float_as_uint(f);
    u = (u + 0x7FFFu + ((u >> 16) & 1u)) >> 16;
    return (unsigned short)u;
}

// ---- block-wide (256 thr) reduction of two sums --------------------------
DEVI void blockReduce2(float& s1, float& s2, float* red){
    #pragma unroll
    for (int m=1;m<64;m<<=1){ s1+=__shfl_xor(s1,m); s2+=__shfl_xor(s2,m); }
    const int w = threadIdx.x>>6;
    if ((threadIdx.x&63)==0){ red[w]=s1; red[8+w]=s2; }
    __syncthreads();
    s1 = red[0]+red[1]+red[2]+red[3];
    s2 = red[8]+red[9]+red[10]+red[11];
}

// ---- generic row LayerNorm (f32 out) -------------------------------------
__global__ __launch_bounds__(256) void ln_rows(const float* __restrict__ in,
                                               const float* __restrict__ g,
                                               const float* __restrict__ bt,
                                               float* __restrict__ out, int C){
    __shared__ float red[16];
    const size_t row = blockIdx.x;
    const float* x = in + row*(size_t)C;
    float s1=0.f, s2=0.f;
    for (int c=threadIdx.x; c<C; c+=256){ float v=x[c]; s1+=v; s2+=v*v; }
    blockReduce2(s1,s2,red);
    const float inv = 1.f/(float)C;
    const float mu = s1*inv;
    const float rs = rsqrtf(s2*inv - mu*mu + 1e-5f);
    float* o = out + row*(size_t)C;
    for (int c=threadIdx.x; c<C; c+=256){
        float y = (x[c]-mu)*rs;
        if (g)  y *= g[c];
        if (bt) y += bt[c];
        o[c] = y;
    }
}

// ---- LayerNorm with bf16 output (C=256, one value per thread) ------------
__global__ __launch_bounds__(256) void ln_rows_bf(const float* __restrict__ in,
                                                  const float* __restrict__ g,
                                                  const float* __restrict__ bt,
                                                  unsigned short* __restrict__ out){
    __shared__ float red[16];
    const size_t row = blockIdx.x;
    const int t = threadIdx.x;
    const float v = in[row*256 + t];
    float s1=v, s2=v*v;
    blockReduce2(s1,s2,red);
    const float mu = s1*(1.f/256.f);
    const float rs = rsqrtf(s2*(1.f/256.f) - mu*mu + 1e-5f);
    out[row*256 + t] = f2bf((v-mu)*rs*g[t] + bt[t]);
}

// ---- concat [Wq | Wkv | Wg] into wcat[256][1024] (f32) --------------------
__global__ __launch_bounds__(256) void concat_w(const float* __restrict__ Wq,
                                                const float* __restrict__ Wkv,
                                                const float* __restrict__ Wg,
                                                float* __restrict__ wcat){
    const int k = blockIdx.x;
    const int t = threadIdx.x;
    wcat[(size_t)k*1024 + t]       = Wq [(size_t)k*256 + t];
    wcat[(size_t)k*1024 + 256 + t] = Wkv[(size_t)k*512 + t];
    wcat[(size_t)k*1024 + 512 + t] = Wkv[(size_t)k*512 + 256 + t];
    wcat[(size_t)k*1024 + 768 + t] = Wg [(size_t)k*256 + t];
}

// ---- cast+transpose: f32 in[K][N] -> bf16 out[N][K] -----------------------
__global__ __launch_bounds__(256) void castT(const float* __restrict__ in,
                                             unsigned short* __restrict__ out,
                                             int K, int N){
    __shared__ unsigned short tile[64][65];
    const int t = threadIdx.x;
    const int nt = blockIdx.x*64, kt = blockIdx.y*64;
    const int c = t & 63, r0 = t >> 6;
    #pragma unroll 4
    for (int rr=r0; rr<64; rr+=4)
        tile[rr][c] = f2bf(in[(size_t)(kt+rr)*N + nt + c]);
    __syncthreads();
    #pragma unroll 4
    for (int rr=r0; rr<64; rr+=4)
        out[(size_t)(nt+rr)*K + kt + c] = tile[c][rr];
}

// ---- K/V transpose: kT/vT[b][d][j] from qkvg ------------------------------
__global__ __launch_bounds__(256) void kvtrans(const float* __restrict__ qkvg,
                                               float* __restrict__ kT,
                                               float* __restrict__ vT){
    __shared__ float tile[64][65];
    const int t = threadIdx.x;
    const int jt = blockIdx.x*64, dt = blockIdx.y*64, b = blockIdx.z;
    const int c = t & 63, r0 = t >> 6;
    #pragma unroll 4
    for (int rr=r0; rr<64; rr+=4)
        tile[rr][c] = qkvg[(size_t)((b<<10)+jt+rr)*1024 + 256 + dt + c];
    __syncthreads();
    #pragma unroll 4
    for (int rr=r0; rr<64; rr+=4)
        kT[((size_t)(b*256 + dt + rr))*1024 + jt + c] = tile[c][rr];
    __syncthreads();
    #pragma unroll 4
    for (int rr=r0; rr<64; rr+=4)
        tile[rr][c] = qkvg[(size_t)((b<<10)+jt+rr)*1024 + 512 + dt + c];
    __syncthreads();
    #pragma unroll 4
    for (int rr=r0; rr<64; rr+=4)
        vT[((size_t)(b*256 + dt + rr))*1024 + jt + c] = tile[c][rr];
}

// ---- MFMA bf16 GEMM: C(MxN f32) = A(MxK bf16) @ Bt(NxK bf16)^T ------------
// 64x64 tile, 4 waves (2x2), each wave 32x32 = 2x2 x mfma_f32_16x16x32_bf16.
// MODE 0: C = A@B            MODE 1: C = resid + (A@B)*mask[m]
// MODE 2: C = resid + sigmoid(gather*mask)*(A@B)*mask[m]
template<int MODE>
__global__ __launch_bounds__(256) void mfma_gemm(
    const unsigned short* __restrict__ A, int lda,
    const unsigned short* __restrict__ Bt, int ldbt,
    float* __restrict__ C, int ldc,
    int K,
    const float* __restrict__ resid,
    const float* __restrict__ mask,
    const float* __restrict__ gsrc,
    const int* __restrict__ idxp)
{
    __shared__ unsigned short As[64*40];
    __shared__ unsigned short Bs[64*40];
    const int t = threadIdx.x;
    const int lane = t & 63, wave = t >> 6;
    const int wr = wave >> 1, wc = wave & 1;
    const int bm = blockIdx.x*64, bn = blockIdx.y*64;
    const int srow = t >> 2, sk = (t & 3) * 8;
    const int l15 = lane & 15, lk = (lane >> 4) * 8;
    f32x4 acc[2][2] = {};
    for (int kt = 0; kt < K; kt += 32){
        *(uint4*)&As[srow*40 + sk] = *(const uint4*)&A [(size_t)(bm+srow)*lda  + kt + sk];
        *(uint4*)&Bs[srow*40 + sk] = *(const uint4*)&Bt[(size_t)(bn+srow)*ldbt + kt + sk];
        __syncthreads();
        bf16x8 a0 = *(const bf16x8*)&As[(32*wr +  0 + l15)*40 + lk];
        bf16x8 a1 = *(const bf16x8*)&As[(32*wr + 16 + l15)*40 + lk];
        bf16x8 b0 = *(const bf16x8*)&Bs[(32*wc +  0 + l15)*40 + lk];
        bf16x8 b1 = *(const bf16x8*)&Bs[(32*wc + 16 + l15)*40 + lk];
        acc[0][0] = __builtin_amdgcn_mfma_f32_16x16x32_bf16(a0,b0,acc[0][0],0,0,0);
        acc[0][1] = __builtin_amdgcn_mfma_f32_16x16x32_bf16(a0,b1,acc[0][1],0,0,0);
        acc[1][0] = __builtin_amdgcn_mfma_f32_16x16x32_bf16(a1,b0,acc[1][0],0,0,0);
        acc[1][1] = __builtin_amdgcn_mfma_f32_16x16x32_bf16(a1,b1,acc[1][1],0,0,0);
        __syncthreads();
    }
    const int rbase = (lane >> 4) * 4;
    #pragma unroll
    for (int m=0;m<2;++m){
        #pragma unroll
        for (int r=0;r<4;++r){
            const int grow = bm + 32*wr + 16*m + rbase + r;
            #pragma unroll
            for (int n=0;n<2;++n){
                const int gcol = bn + 32*wc + 16*n + l15;
                float v = acc[m][n][r];
                if (MODE==0){
                    C[(size_t)grow*ldc + gcol] = v;
                } else if (MODE==1){
                    const float mi = mask[grow];
                    C[(size_t)grow*ldc + gcol] = resid[(size_t)grow*256 + gcol] + v*mi;
                } else {
                    const float mi = mask[grow];
                    const int id = idxp[grow];
                    const int bbi = grow >> 10;
                    const float cg = gsrc[((size_t)(bbi*256+id))*256 + gcol]*mi;
                    C[(size_t)grow*ldc + gcol] = resid[(size_t)grow*256 + gcol] + sigm(cg)*v*mi;
                }
            }
        }
    }
}

// ---- MFMA dual: bmid(bf16) = silu(A@W1) * (A@W2), Bt inputs ---------------
__global__ __launch_bounds__(256) void mfma_dual(
    const unsigned short* __restrict__ A, int lda,
    const unsigned short* __restrict__ B1t,
    const unsigned short* __restrict__ B2t, int ldbt,
    unsigned short* __restrict__ C, int ldc,
    int K)
{
    __shared__ unsigned short As[64*40];
    __shared__ unsigned short B1s[64*40];
    __shared__ unsigned short B2s[64*40];
    const int t = threadIdx.x;
    const int lane = t & 63, wave = t >> 6;
    const int wr = wave >> 1, wc = wave & 1;
    const int bm = blockIdx.x*64, bn = blockIdx.y*64;
    const int srow = t >> 2, sk = (t & 3) * 8;
    const int l15 = lane & 15, lk = (lane >> 4) * 8;
    f32x4 acc1[2][2] = {};
    f32x4 acc2[2][2] = {};
    for (int kt = 0; kt < K; kt += 32){
        *(uint4*)&As [srow*40 + sk] = *(const uint4*)&A  [(size_t)(bm+srow)*lda  + kt + sk];
        *(uint4*)&B1s[srow*40 + sk] = *(const uint4*)&B1t[(size_t)(bn+srow)*ldbt + kt + sk];
        *(uint4*)&B2s[srow*40 + sk] = *(const uint4*)&B2t[(size_t)(bn+srow)*ldbt + kt + sk];
        __syncthreads();
        bf16x8 a0 = *(const bf16x8*)&As[(32*wr +  0 + l15)*40 + lk];
        bf16x8 a1 = *(const bf16x8*)&As[(32*wr + 16 + l15)*40 + lk];
        bf16x8 p0 = *(const bf16x8*)&B1s[(32*wc +  0 + l15)*40 + lk];
        bf16x8 p1 = *(const bf16x8*)&B1s[(32*wc + 16 + l15)*40 + lk];
        bf16x8 q0 = *(const bf16x8*)&B2s[(32*wc +  0 + l15)*40 + lk];
        bf16x8 q1 = *(const bf16x8*)&B2s[(32*wc + 16 + l15)*40 + lk];
        acc1[0][0] = __builtin_amdgcn_mfma_f32_16x16x32_bf16(a0,p0,acc1[0][0],0,0,0);
        acc1[0][1] = __builtin_amdgcn_mfma_f32_16x16x32_bf16(a0,p1,acc1[0][1],0,0,0);
        acc1[1][0] = __builtin_amdgcn_mfma_f32_16x16x32_bf16(a1,p0,acc1[1][0],0,0,0);
        acc1[1][1] = __builtin_amdgcn_mfma_f32_16x16x32_bf16(a1,p1,acc1[1][1],0,0,0);
        acc2[0][0] = __builtin_amdgcn_mfma_f32_16x16x32_bf16(a0,q0,acc2[0][0],0,0,0);
        acc2[0][1] = __builtin_amdgcn_mfma_f32_16x16x32_bf16(a0,q1,acc2[0][1],0,0,0);
        acc2[1][0] = __builtin_amdgcn_mfma_f32_16x16x32_bf16(a1,q0,acc2[1][0],0,0,0);
        acc2[1][1] = __builtin_amdgcn_mfma_f32_16x16x32_bf16(a1,q1,acc2[1][1],0,0,0);
        __syncthreads();
    }
    const int rbase = (lane >> 4) * 4;
    #pragma unroll
    for (int m=0;m<2;++m){
        #pragma unroll
        for (int r=0;r<4;++r){
            const int grow = bm + 32*wr + 16*m + rbase + r;
            #pragma unroll
            for (int n=0;n<2;++n){
                const int gcol = bn + 32*wc + 16*n + l15;
                const float u1 = acc1[m][n][r];
                C[(size_t)grow*ldc + gcol] = f2bf(u1*sigm(u1)*acc2[m][n][r]);
            }
        }
    }
}

// ---- tiled f32 GEMM (small conditioning mats): MODE 0 only ----------------
__global__ __launch_bounds__(256) void gemm_t(
    const float* __restrict__ A, int lda,
    const float* __restrict__ B, int ldb,
    float* __restrict__ C, int ldc,
    int M, int N, int K,
    const float* __restrict__ bias)
{
    __shared__ float As[16][68];
    __shared__ float Bs[16][68];
    const int t = threadIdx.x;
    const int tx = t & 15, ty = t >> 4;
    const int bm = blockIdx.x * 64, bn = blockIdx.y * 64;
    const int am = t >> 2, akq = (t & 3) * 4;
    const int bk = t >> 4, bnq = (t & 15) * 4;
    float acc[4][4] = {};
    for (int kt = 0; kt < K; kt += 16) {
        const float4 va = *(const float4*)&A[(size_t)(bm+am)*lda + kt + akq];
        const float4 vb = *(const float4*)&B[(size_t)(kt+bk)*ldb + bn + bnq];
        As[akq+0][am]=va.x; As[akq+1][am]=va.y; As[akq+2][am]=va.z; As[akq+3][am]=va.w;
        *(float4*)&Bs[bk][bnq] = vb;
        __syncthreads();
        #pragma unroll
        for (int kk=0; kk<16; ++kk){
            const float4 af = *(const float4*)&As[kk][ty*4];
            const float4 bf = *(const float4*)&Bs[kk][tx*4];
            acc[0][0]+=af.x*bf.x; acc[0][1]+=af.x*bf.y; acc[0][2]+=af.x*bf.z; acc[0][3]+=af.x*bf.w;
            acc[1][0]+=af.y*bf.x; acc[1][1]+=af.y*bf.y; acc[1][2]+=af.y*bf.z; acc[1][3]+=af.y*bf.w;
            acc[2][0]+=af.z*bf.x; acc[2][1]+=af.z*bf.y; acc[2][2]+=af.z*bf.z; acc[2][3]+=af.z*bf.w;
            acc[3][0]+=af.w*bf.x; acc[3][1]+=af.w*bf.y; acc[3][2]+=af.w*bf.z; acc[3][3]+=af.w*bf.w;
        }
        __syncthreads();
    }
    #pragma unroll
    for (int i=0;i<4;++i){
        const int m = bm + ty*4 + i;
        #pragma unroll
        for (int jj=0;jj<4;++jj){
            const int n = bn + tx*4 + jj;
            float v = acc[i][jj];
            if (bias) v += bias[n];
            C[(size_t)m*ldc+n] = v;
        }
    }
}

// ---- pair-bias precompute (unchanged from R6) -----------------------------
__global__ __launch_bounds__(256,4) void pb_kernel(
    const float* __restrict__ fp,
    const float* __restrict__ lnzg, const float* __restrict__ lnzb,
    const float* __restrict__ wbias,
    const float* __restrict__ mask,
    float* __restrict__ pb)
{
    __shared__ float S[8][1032];
    __shared__ float maskS[1024];
    const int t = threadIdx.x;
    const int bi = blockIdx.x;
    const int b = bi >> 10, i = bi & 1023;
    const int l = t & 15, grp = t >> 4;

    float wg[4], wb_[4];
    fv4 w0[4], w1[4];
    #pragma unroll
    for (int cc=0; cc<4; ++cc){
        const int c = 4*l + cc;
        wg[cc] = lnzg[c]; wb_[cc] = lnzb[c];
        w0[cc] = *(const fv4*)&wbias[c*8];
        w1[cc] = *(const fv4*)&wbias[c*8+4];
    }
    *(fv4*)&maskS[t*4] = ((const fv4*)(mask + (b<<10)))[t];
    __syncthreads();
    const float mi = mask[bi];

    const fv4* fpv = (const fv4*)(fp + (size_t)bi*65536);
    fv4 cur = fpv[(size_t)grp*16 + l];
    #pragma unroll 1
    for (int jt=0; jt<1024; jt+=16){
        const int j = jt + grp;
        const fv4 f = cur;
        if (jt+16 < 1024) cur = fpv[(size_t)(j+16)*16 + l];
        float s1 = f.x+f.y+f.z+f.w;
        float s2 = f.x*f.x+f.y*f.y+f.z*f.z+f.w*f.w;
        #pragma unroll
        for (int m=1;m<16;m<<=1){ s1 += __shfl_xor(s1,m); s2 += __shfl_xor(s2,m); }
        const float mu = s1*(1.f/64.f);
        const float rs = rsqrtf(s2*(1.f/64.f) - mu*mu + 1e-5f);
        float lnv[4];
        lnv[0]=(f.x-mu)*rs*wg[0]+wb_[0];
        lnv[1]=(f.y-mu)*rs*wg[1]+wb_[1];
        lnv[2]=(f.z-mu)*rs*wg[2]+wb_[2];
        lnv[3]=(f.w-mu)*rs*wg[3]+wb_[3];
        float pv[8] = {};
        #pragma unroll
        for (int cc=0;cc<4;++cc){
            pv[0]+=lnv[cc]*w0[cc].x; pv[1]+=lnv[cc]*w0[cc].y;
            pv[2]+=lnv[cc]*w0[cc].z; pv[3]+=lnv[cc]*w0[cc].w;
            pv[4]+=lnv[cc]*w1[cc].x; pv[5]+=lnv[cc]*w1[cc].y;
            pv[6]+=lnv[cc]*w1[cc].z; pv[7]+=lnv[cc]*w1[cc].w;
        }
        {
            const bool b8 = (l & 8);
            #pragma unroll
            for (int k=0;k<4;++k){
                const float a = b8 ? pv[k] : pv[k+4];
                const float r = __shfl_xor(a, 8);
                pv[k] = (b8 ? pv[k+4] : pv[k]) + r;
            }
            const bool b4 = (l & 4);
            #pragma unroll
            for (int k=0;k<2;++k){
                const float a = b4 ? pv[k] : pv[k+2];
                const float r = __shfl_xor(a, 4);
                pv[k] = (b4 ? pv[k+2] : pv[k]) + r;
            }
            const bool b2 = (l & 2);
            {
                const float a = b2 ? pv[0] : pv[1];
                const float r = __shfl_xor(a, 2);
                pv[0] = (b2 ? pv[1] : pv[0]) + r;
            }
            pv[0] += __shfl_xor(pv[0], 1);
        }
        if ((l & 1) == 0){
            const float mterm = (mi*maskS[j]-1.f)*100000.f;
            S[(l>>1)][j] = pv[0] + mterm;
        }
    }
    __syncthreads();
    #pragma unroll 1
    for (int k=0;k<8;++k){
        const int j4 = (t & 255) * 4;
        const fv4 v = *(const fv4*)&S[k][j4];
        *(fv4*)&pb[(((size_t)(b*8+k))*1024 + i)*1024 + j4] = v;
    }
}

// ---- attention (R7 structure), og output bf16 -----------------------------
__global__ __launch_bounds__(256,4) void attn_tile(
    const float* __restrict__ qkvg,
    const float* __restrict__ kT,
    const float* __restrict__ vT,
    const float* __restrict__ pb,
    unsigned short* __restrict__ og)
{
    __shared__ float S[8][1032];
    __shared__ float qs[8][33];
    __shared__ float denomS[8];
    const int t = threadIdx.x;
    const int it = blockIdx.x;
    const int h  = blockIdx.y;
    const int b  = blockIdx.z;
    const int i0 = it*8;
    const int r = t >> 5, jl = t & 31;
    qs[r][jl] = qkvg[((size_t)(b*1024 + i0 + r))*1024 + h*32 + jl];
    float q[32];
    #pragma unroll
    for (int d=0; d<32; ++d) q[d] = qs[r][d];

    const float scale = 0.17677669529663687f;
    const float* kTb = kT + ((size_t)b*256 + h*32)*1024;
    const float* pbr = pb + (((size_t)(b*8+h))*1024 + i0 + r)*1024;
    for (int jt=0; jt<1024; jt+=64){
        const int j0 = jt + jl*2;
        float a0=0.f, a1=0.f;
        #pragma unroll
        for (int d=0; d<32; ++d){
            const float2 k2 = *(const float2*)(kTb + (size_t)d*1024 + j0);
            a0 += q[d]*k2.x; a1 += q[d]*k2.y;
        }
        const float2 pb2 = *(const float2*)(pbr + j0);
        S[r][j0]   = a0*scale + pb2.x;
        S[r][j0+1] = a1*scale + pb2.y;
    }
    {
        float mx = -3.4e38f;
        for (int jj=jl; jj<1024; jj+=32) mx = fmaxf(mx, S[r][jj]);
        #pragma unroll
        for (int off=16; off>0; off>>=1) mx = fmaxf(mx, __shfl_xor(mx, off, 32));
        float sum = 0.f;
        for (int jj=jl; jj<1024; jj+=32){
            const float e = __expf(S[r][jj]-mx);
            S[r][jj] = e;
            sum += e;
        }
        #pragma unroll
        for (int off=16; off>0; off>>=1) sum += __shfl_xor(sum, off, 32);
        if (jl==0) denomS[r] = sum;
    }
    float acc[32];
    const float* vTb = vT + ((size_t)b*256 + h*32)*1024;
    #pragma unroll
    for (int d=0; d<32; ++d){
        const fv4* vrow4 = (const fv4*)(vTb + (size_t)d*1024);
        float a0 = 0.f;
        #pragma unroll
        for (int k=0;k<8;++k){
            const fv4 vv = vrow4[k*32 + jl];
            const fv4 pp = *(const fv4*)&S[r][(k*32 + jl)*4];
            a0 += pp.x*vv.x + pp.y*vv.y + pp.z*vv.z + pp.w*vv.w;
        }
        acc[d] = a0;
    }
    {
        const bool c16 = jl & 16;
        #pragma unroll
        for (int k=0;k<16;++k){
            const float a = c16 ? acc[k] : acc[k+16];
            const float rr = __shfl_xor(a, 16);
            acc[k] = (c16 ? acc[k+16] : acc[k]) + rr;
        }
        const bool c8 = jl & 8;
        #pragma unroll
        for (int k=0;k<8;++k){
            const float a = c8 ? acc[k] : acc[k+8];
            const float rr = __shfl_xor(a, 8);
            acc[k] = (c8 ? acc[k+8] : acc[k]) + rr;
        }
        const bool c4 = jl & 4;
        #pragma unroll
        for (int k=0;k<4;++k){
            const float a = c4 ? acc[k] : acc[k+4];
            const float rr = __shfl_xor(a, 4);
            acc[k] = (c4 ? acc[k+4] : acc[k]) + rr;
        }
        const bool c2 = jl & 2;
        #pragma unroll
        for (int k=0;k<2;++k){
            const float a = c2 ? acc[k] : acc[k+2];
            const float rr = __shfl_xor(a, 2);
            acc[k] = (c2 ? acc[k+2] : acc[k]) + rr;
        }
        const bool c1 = jl & 1;
        {
            const float a = c1 ? acc[0] : acc[1];
            const float rr = __shfl_xor(a, 1);
            acc[0] = (c1 ? acc[1] : acc[0]) + rr;
        }
    }
    const int row = b*1024 + i0 + r;
    const float gpre = qkvg[(size_t)row*1024 + 768 + h*32 + jl];
    og[(size_t)row*256 + h*32 + jl] = f2bf((acc[0]/denomS[r]) * sigm(gpre));
}

// ---- sa = LN(rig)*sigmoid(cond_gate) + cond_bias  (bf16 out) --------------
__global__ __launch_bounds__(256) void sa_kernel(
    const float* __restrict__ rig,
    const float* __restrict__ c1res,
    const float* __restrict__ cbres,
    const int* __restrict__ idxp,
    const float* __restrict__ mask,
    unsigned short* __restrict__ sa)
{
    __shared__ float red[16];
    const int m = blockIdx.x;
    const int t = threadIdx.x;
    const float v = rig[(size_t)m*256 + t];
    float s1 = v, s2 = v*v;
    blockReduce2(s1,s2,red);
    const float mu = s1*(1.f/256.f);
    const float rs = rsqrtf(s2*(1.f/256.f) - mu*mu + 1e-5f);
    const float sn = (v-mu)*rs;
    const float mi = mask[m];
    const int id = idxp[m];
    const int b = m >> 10;
    const size_t go = ((size_t)(b*256+id))*256 + t;
    const float cgate = c1res[go]*mi;
    const float cb    = cbres[go]*mi;
    sa[(size_t)m*256+t] = f2bf(sn*sigm(cgate) + cb);
}

extern "C" void kernel_launch(void* const* d_in, const int* in_sizes, int n_in,
                              void* d_out, int out_size, void* d_ws, size_t ws_size,
                              hipStream_t stream)
{
    (void)in_sizes; (void)n_in; (void)out_size; (void)ws_size;
    const float* s_     = (const float*)d_in[0];
    const float* rigids = (const float*)d_in[1];
    const float* fp     = (const float*)d_in[2];
    const float* maskp  = (const float*)d_in[3];
    const int*   idxp   = (const int*)d_in[4];
    const float* ln_g   = (const float*)d_in[5];
    const float* ln_b   = (const float*)d_in[6];
    const float* Wq     = (const float*)d_in[7];
    const float* Wkv    = (const float*)d_in[8];
    const float* lnz_g  = (const float*)d_in[9];
    const float* lnz_b  = (const float*)d_in[10];
    const float* Wbias  = (const float*)d_in[11];
    const float* Wg     = (const float*)d_in[12];
    const float* Wo     = (const float*)d_in[13];
    const float* lncond = (const float*)d_in[14];
    const float* Wc1    = (const float*)d_in[15];
    const float* bc1    = (const float*)d_in[16];
    const float* Wcn    = (const float*)d_in[17];
    const float* W1     = (const float*)d_in[18];
    const float* W2     = (const float*)d_in[19];
    const float* Wc2    = (const float*)d_in[20];
    const float* bc2    = (const float*)d_in[21];
    const float* Wb     = (const float*)d_in[22];
    float* out = (float*)d_out;

    float* ws    = (float*)d_ws;
    float* qkvg  = ws;                  // 2048*1024 f32
    float* rig   = qkvg  + 2097152;     // 2048*256 f32
    float* cn    = rig   + 524288;      // 512*384 f32
    float* c1res = cn    + 196608;      // 512*256
    float* cbres = c1res + 131072;      // 512*256
    float* cgres = cbres + 131072;      // 512*256
    float* kT    = cgres + 131072;      // 2*256*1024
    float* vT    = kT    + 524288;      // 2*256*1024
    float* wcat  = vT    + 524288;      // 256*1024 f32
    float* pbuf  = wcat  + 262144;      // 2*8*1024*1024 = 64 MB
    float* bend  = pbuf  + 16777216;
    unsigned short* xbf    = (unsigned short*)bend;        // 2048*256
    unsigned short* ogbf   = xbf    + 524288;              // 2048*256
    unsigned short* sabf   = ogbf   + 524288;              // 2048*256
    unsigned short* bmidbf = sabf   + 524288;              // 2048*512
    unsigned short* wcatT  = bmidbf + 1048576;             // 1024*256
    unsigned short* WoT    = wcatT  + 262144;              // 256*256
    unsigned short* W1T    = WoT    + 65536;               // 512*256
    unsigned short* W2T    = W1T    + 131072;              // 512*256
    unsigned short* WbT    = W2T    + 131072;              // 256*512

    // 512 MB stream first, then everything else (cache-friendly order)
    pb_kernel<<<2048,256,0,stream>>>(fp, lnz_g, lnz_b, Wbias, maskp, pbuf);
    concat_w<<<256,256,0,stream>>>(Wq, Wkv, Wg, wcat);
    castT<<<dim3(16,4),256,0,stream>>>(wcat, wcatT, 256, 1024);
    castT<<<dim3(4,4),256,0,stream>>>(Wo, WoT, 256, 256);
    castT<<<dim3(8,4),256,0,stream>>>(W1, W1T, 256, 512);
    castT<<<dim3(8,4),256,0,stream>>>(W2, W2T, 256, 512);
    castT<<<dim3(4,8),256,0,stream>>>(Wb, WbT, 512, 256);
    ln_rows_bf<<<2048,256,0,stream>>>(rigids, ln_g, ln_b, xbf);
    mfma_gemm<0><<<dim3(32,16),256,0,stream>>>(xbf,256, wcatT,256, qkvg,1024, 256, nullptr,nullptr,nullptr,nullptr);
    kvtrans<<<dim3(16,4,2),256,0,stream>>>(qkvg, kT, vT);
    attn_tile<<<dim3(128,8,2),256,0,stream>>>(qkvg, kT, vT, pbuf, ogbf);
    mfma_gemm<1><<<dim3(32,4),256,0,stream>>>(ogbf,256, WoT,256, rig,256, 256, rigids, maskp, nullptr,nullptr);
    ln_rows<<<512,256,0,stream>>>(s_, lncond, nullptr, cn, 384);
    gemm_t<<<dim3(8,4),256,0,stream>>>(cn,384, Wc1,256, c1res,256, 512,256,384, bc1);
    gemm_t<<<dim3(8,4),256,0,stream>>>(cn,384, Wcn,256, cbres,256, 512,256,384, nullptr);
    gemm_t<<<dim3(8,4),256,0,stream>>>(s_,384, Wc2,256, cgres,256, 512,256,384, bc2);
    sa_kernel<<<2048,256,0,stream>>>(rig, c1res, cbres, idxp, maskp, sabf);
    mfma_dual<<<dim3(32,8),256,0,stream>>>(sabf,256, W1T, W2T,256, bmidbf,512, 256);
    mfma_gemm<2><<<dim3(32,4),256,0,stream>>>(bmidbf,512, WbT,512, out,256, 512, rig, maskp, cgres, idxp);
}